// Round 1
// 543.380 us; speedup vs baseline: 1.1403x; 1.1403x over previous
//
#include <hip/hip_runtime.h>
#include <math.h>

#define HW   16384           // 128*128
#define PS   16900           // 130*130 f32 padded plane
#define PSH  17160           // 130*132 bf16 padded plane (stride 132)
#define SH   132

typedef __attribute__((ext_vector_type(8))) short bf16x8;
typedef __attribute__((ext_vector_type(4))) float f32x4;

__device__ inline unsigned short f2bf(float x) {
    unsigned int u = __float_as_uint(x);
    unsigned int r = (u + 0x7fffu + ((u >> 16) & 1u)) >> 16;
    return (unsigned short)r;
}
__device__ inline float bf2f(unsigned short h) {
    return __uint_as_float(((unsigned int)h) << 16);
}

// ---- zero the pad ring of nch bf16 padded planes (stride 132) --------------
__global__ __launch_bounds__(256) void zero_ring_h_k(unsigned short* __restrict__ base, int nch) {
    int t = blockIdx.x * 256 + threadIdx.x;
    if (t >= nch * 520) return;
    int ch = t / 520, rp = t - ch * 520;
    int row, col;
    if (rp < 132)      { row = 0;   col = rp; }
    else if (rp < 264) { row = 129; col = rp - 132; }
    else {
        int rem = rp - 264;
        if (rem >= 256) return;            // rows 1..128 only (no OOB spill)
        row = 1 + (rem >> 1); col = (rem & 1) ? 129 : 0;
    }
    base[(size_t)ch * PSH + row * SH + col] = 0;
}

// ---- zero ccT ring pixels for channels 256..511 (Cf) -----------------------
__global__ __launch_bounds__(256) void ringT_k(unsigned short* __restrict__ ccT) {
    int t = blockIdx.x * 256 + threadIdx.x;
    if (t >= 520 * 256) return;
    int ci = t & 255, rp = t >> 8;
    int row, col;
    if (rp < 130)      { row = 0;   col = rp; }
    else if (rp < 260) { row = 129; col = rp - 130; }
    else {
        int rem = rp - 260;
        if (rem >= 256) return;            // rows 1..128 only (no OOB spill)
        row = 1 + (rem >> 1); col = (rem & 1) ? 129 : 0;
    }
    ccT[(size_t)(row * 130 + col) * 512 + 256 + ci] = 0;
}

// ---- bilinear upsample (align_corners) 32x32 -> 128x128, into 256 f32 planes
__global__ __launch_bounds__(256) void upsample_k(const float* __restrict__ x,
                                                  float* __restrict__ ccpad) {
    int c = blockIdx.y;
    int idx = blockIdx.x * 256 + threadIdx.x;
    if (idx >= PS) return;
    int r = idx / 130, s = idx - r * 130;
    float val = 0.0f;
    if (r >= 1 && r <= 128 && s >= 1 && s <= 128) {
        int i = r - 1, j = s - 1;
        float yf = (float)i * (31.0f / 127.0f);
        float xf = (float)j * (31.0f / 127.0f);
        int y0 = min((int)yf, 31); int y1 = min(y0 + 1, 31);
        int x0 = min((int)xf, 31); int x1 = min(x0 + 1, 31);
        float wy = yf - (float)y0, wx = xf - (float)x0;
        const float* xc = x + (size_t)c * 1024;
        float a = xc[y0 * 32 + x0] * (1.0f - wx) + xc[y0 * 32 + x1] * wx;
        float b = xc[y1 * 32 + x0] * (1.0f - wx) + xc[y1 * 32 + x1] * wx;
        val = a * (1.0f - wy) + b * wy;
    }
    ccpad[(size_t)c * PS + idx] = val;
}

// ---- flat transpose+cvt: src f32 [256][npx] -> dst bf16 [npx][256] ---------
__global__ __launch_bounds__(256) void cvtT_flat_k(const float* __restrict__ src,
                                                   unsigned short* __restrict__ dst,
                                                   int npx) {
    int t = blockIdx.x * 256 + threadIdx.x;    // (pix, c), c fastest
    int c = t & 255, pix = t >> 8;
    dst[t] = f2bf(src[(size_t)c * npx + pix]);
}

// ---- ccpad f32 planes (256 ch, stride 130) -> ccT[pix][512] ch 0..255 ------
__global__ __launch_bounds__(256) void cvtT_k(const float* __restrict__ src,
                                              unsigned short* __restrict__ dst) {
    int t = blockIdx.x * 256 + threadIdx.x;    // 130*130*256 exactly
    int c = t & 255, pix = t >> 8;
    dst[(size_t)pix * 512 + c] = f2bf(src[(size_t)c * PS + pix]);
}

// ---- fm_w / fs_w (256x256 f32) -> bf16 -------------------------------------
__global__ __launch_bounds__(256) void w2bf_k(const float* __restrict__ a,
                                              const float* __restrict__ b,
                                              unsigned short* __restrict__ da,
                                              unsigned short* __restrict__ db) {
    int t = blockIdx.x * 256 + threadIdx.x;
    if (t >= 65536) return;
    da[t] = f2bf(a[t]);
    db[t] = f2bf(b[t]);
}

// ---- u[c,h,w] = sum_k L[c,h,k]*v[c,k,w] + L[c,h,w] (f32) -------------------
__global__ __launch_bounds__(256) void u_matmul_k(const float* __restrict__ llf,
                                                  const float* __restrict__ v,
                                                  float* __restrict__ u) {
    int c = blockIdx.y;
    const float* L = llf + (size_t)c * HW;
    const float* V = v   + (size_t)c * HW;
    float*       U = u   + (size_t)c * HW;
    int tid = threadIdx.x;
    int ty = tid >> 4, tx = tid & 15;
    int r0 = (blockIdx.x << 6) + (ty << 2);
    int w0 = tx << 3;
    float acc[4][8] = {};
    for (int k = 0; k < 128; ++k) {
        float a[4];
#pragma unroll
        for (int i = 0; i < 4; ++i) a[i] = L[(r0 + i) * 128 + k];
        float4 b0 = *(const float4*)(V + k * 128 + w0);
        float4 b1 = *(const float4*)(V + k * 128 + w0 + 4);
        float bv[8] = {b0.x, b0.y, b0.z, b0.w, b1.x, b1.y, b1.z, b1.w};
#pragma unroll
        for (int i = 0; i < 4; ++i)
#pragma unroll
            for (int j = 0; j < 8; ++j) acc[i][j] += a[i] * bv[j];
    }
#pragma unroll
    for (int i = 0; i < 4; ++i) {
#pragma unroll
        for (int j = 0; j < 8; ++j) acc[i][j] += L[(r0 + i) * 128 + w0 + j];
        *(float4*)(U + (r0 + i) * 128 + w0)     = make_float4(acc[i][0], acc[i][1], acc[i][2], acc[i][3]);
        *(float4*)(U + (r0 + i) * 128 + w0 + 4) = make_float4(acc[i][4], acc[i][5], acc[i][6], acc[i][7]);
    }
}

// ---- weights (O,C,3,3) f32 -> [k][o][c] bf16 (O=256) -----------------------
__global__ __launch_bounds__(256) void tr_ocK_k(const float* __restrict__ w,
                                                unsigned short* __restrict__ dst, int C) {
    int t = blockIdx.x * 256 + threadIdx.x;
    if (t >= 9 * 256 * C) return;
    int c = t % C; int rest = t / C; int o = rest & 255; int k = rest >> 8;
    dst[t] = f2bf(w[(size_t)o * C * 9 + c * 9 + k]);
}

// ---- p_w (18,512,3,3) f32 -> [k][32][512] bf16, zero-padded to 32 o --------
__global__ __launch_bounds__(256) void tr_pw_k(const float* __restrict__ w,
                                               unsigned short* __restrict__ dst) {
    int t = blockIdx.x * 256 + threadIdx.x;
    if (t >= 9 * 32 * 512) return;
    int c = t & 511; int rest = t >> 9; int o = rest & 31; int k = rest >> 5;
    dst[t] = (o < 18) ? f2bf(w[(size_t)o * 4608 + c * 9 + k]) : (unsigned short)0;
}

// ============ 1x1 GEMM (K=256) 256o x 32px MFMA + sigmoid -> f32 planes =====
__global__ __launch_bounds__(256, 2) void vmfma_k(
        const unsigned short* __restrict__ inT,   // [HW][256] bf16
        const unsigned short* __restrict__ wh,    // [256][256] bf16
        float* __restrict__ vout) {               // [256][HW] f32
    __shared__ __align__(16) unsigned short Bs[32][72];
    int b = blockIdx.x;
    int xcd = b & 7, sl = b >> 3;
    int nt = (xcd << 6) + sl;
    int hrow = nt >> 2, pc0 = (nt & 3) << 5;
    int tid = threadIdx.x;
    int wv = tid >> 6, lane = tid & 63;
    int lr = lane & 15, lg = lane >> 4;
    // staging map: 8 adjacent lanes cover 128 contiguous B of one pixel row
    int pxs = tid >> 3, cg8 = tid & 7;
    int p = (hrow << 7) + pc0 + pxs;
    f32x4 acc[4][2];
#pragma unroll
    for (int i = 0; i < 4; ++i)
#pragma unroll
        for (int j = 0; j < 2; ++j) acc[i][j] = (f32x4){0.f, 0.f, 0.f, 0.f};
    for (int ks = 0; ks < 256; ks += 64) {
        __syncthreads();
        *(bf16x8*)&Bs[pxs][cg8 << 3] =
            *(const bf16x8*)(inT + (size_t)p * 256 + ks + (cg8 << 3));
        __syncthreads();
#pragma unroll
        for (int s = 0; s < 2; ++s) {
            int ko = ks + (s << 5) + (lg << 3);
            bf16x8 af[4], bfr[2];
#pragma unroll
            for (int mi = 0; mi < 4; ++mi)
                af[mi] = *(const bf16x8*)(wh + (size_t)((wv << 6) + (mi << 4) + lr) * 256 + ko);
#pragma unroll
            for (int ni = 0; ni < 2; ++ni)
                bfr[ni] = *(const bf16x8*)(&Bs[(ni << 4) + lr][(s << 5) + (lg << 3)]);
#pragma unroll
            for (int mi = 0; mi < 4; ++mi)
#pragma unroll
                for (int ni = 0; ni < 2; ++ni)
                    acc[mi][ni] = __builtin_amdgcn_mfma_f32_16x16x32_bf16(
                        af[mi], bfr[ni], acc[mi][ni], 0, 0, 0);
        }
    }
#pragma unroll
    for (int mi = 0; mi < 4; ++mi)
#pragma unroll
        for (int ni = 0; ni < 2; ++ni)
#pragma unroll
            for (int r = 0; r < 4; ++r) {
                int o   = (wv << 6) + (mi << 4) + (lg << 2) + r;
                int pxx = pc0 + (ni << 4) + lr;
                vout[(size_t)o * HW + (hrow << 7) + pxx] =
                    1.0f / (1.0f + expf(-acc[mi][ni][r]));
            }
}

// ============ 1x1 GEMM (K=256) Cf -> ccT channels 256..511 ==================
__global__ __launch_bounds__(256, 2) void cfmfma_k(
        const unsigned short* __restrict__ inT,   // uT [HW][256] bf16
        const unsigned short* __restrict__ wh,    // fs_w [256][256] bf16
        unsigned short* __restrict__ ccT) {       // [130*130][512] bf16
    __shared__ __align__(16) unsigned short Bs[32][72];
    int b = blockIdx.x;
    int xcd = b & 7, sl = b >> 3;
    int nt = (xcd << 6) + sl;
    int hrow = nt >> 2, pc0 = (nt & 3) << 5;
    int tid = threadIdx.x;
    int wv = tid >> 6, lane = tid & 63;
    int lr = lane & 15, lg = lane >> 4;
    int pxs = tid >> 3, cg8 = tid & 7;
    int p = (hrow << 7) + pc0 + pxs;
    f32x4 acc[4][2];
#pragma unroll
    for (int i = 0; i < 4; ++i)
#pragma unroll
        for (int j = 0; j < 2; ++j) acc[i][j] = (f32x4){0.f, 0.f, 0.f, 0.f};
    for (int ks = 0; ks < 256; ks += 64) {
        __syncthreads();
        *(bf16x8*)&Bs[pxs][cg8 << 3] =
            *(const bf16x8*)(inT + (size_t)p * 256 + ks + (cg8 << 3));
        __syncthreads();
#pragma unroll
        for (int s = 0; s < 2; ++s) {
            int ko = ks + (s << 5) + (lg << 3);
            bf16x8 af[4], bfr[2];
#pragma unroll
            for (int mi = 0; mi < 4; ++mi)
                af[mi] = *(const bf16x8*)(wh + (size_t)((wv << 6) + (mi << 4) + lr) * 256 + ko);
#pragma unroll
            for (int ni = 0; ni < 2; ++ni)
                bfr[ni] = *(const bf16x8*)(&Bs[(ni << 4) + lr][(s << 5) + (lg << 3)]);
#pragma unroll
            for (int mi = 0; mi < 4; ++mi)
#pragma unroll
                for (int ni = 0; ni < 2; ++ni)
                    acc[mi][ni] = __builtin_amdgcn_mfma_f32_16x16x32_bf16(
                        af[mi], bfr[ni], acc[mi][ni], 0, 0, 0);
        }
    }
#pragma unroll
    for (int mi = 0; mi < 4; ++mi)
#pragma unroll
        for (int ni = 0; ni < 2; ++ni) {
            int pxx = pc0 + (ni << 4) + lr;
            int pix = (hrow + 1) * 130 + pxx + 1;
            unsigned short pk[4];
#pragma unroll
            for (int r = 0; r < 4; ++r) pk[r] = f2bf(acc[mi][ni][r]);
            *(ushort4*)(ccT + (size_t)pix * 512 + 256 + (wv << 6) + (mi << 4) + (lg << 2))
                = *(ushort4*)pk;
        }
}

// ============ offset conv 512->18: channel-split partials, ccT staging ======
__global__ __launch_bounds__(256, 2) void off_part_k(
        const unsigned short* __restrict__ ccT,   // [130*130][512] bf16
        const unsigned short* __restrict__ pwTh,  // [9][32][512] bf16
        float* __restrict__ pbuf) {               // [4][32][HW] f32
    __shared__ __align__(16) unsigned short Bs[128][40];
    int b = blockIdx.x;
    int xcd = b & 7, slot = b >> 3;               // 64 slots
    int hrow = (xcd << 4) + (slot >> 2);
    int cg = slot & 3, c0 = cg << 7;
    int tid = threadIdx.x;
    int wv = tid >> 6, lane = tid & 63;
    int wr = wv >> 1, wc = wv & 1;                // o-half(16) x px-half(64)
    int lr = lane & 15, lg = lane >> 4;
    // staging map: 4 adjacent lanes cover the full 64B ch-window of one pixel
    int c4 = tid & 3, pxs = tid >> 2;             // pxs in 0..63, 2 px passes
    f32x4 acc[4];
#pragma unroll
    for (int j = 0; j < 4; ++j) acc[j] = (f32x4){0.f, 0.f, 0.f, 0.f};

    for (int kt = 0; kt < 9; ++kt) {
        int dy = kt / 3 - 1, dx = kt % 3 - 1;
        int pixb = (hrow + dy + 1) * 130 + dx + 1;
        for (int ksl = 0; ksl < 128; ksl += 32) {
            __syncthreads();
#pragma unroll
            for (int pp = 0; pp < 2; ++pp) {
                int px = pxs + (pp << 6);
                *(bf16x8*)&Bs[px][c4 << 3] =
                    *(const bf16x8*)(ccT + (size_t)(pixb + px) * 512 + c0 + ksl + (c4 << 3));
            }
            __syncthreads();
            bf16x8 af, bfr[4];
            af = *(const bf16x8*)(pwTh + (size_t)kt * 16384
                                  + (size_t)((wr << 4) + lr) * 512 + c0 + ksl + (lg << 3));
#pragma unroll
            for (int ni = 0; ni < 4; ++ni) {
                int n = (wc << 6) + (ni << 4) + lr;
                bfr[ni] = *(const bf16x8*)(&Bs[n][lg << 3]);
            }
#pragma unroll
            for (int ni = 0; ni < 4; ++ni)
                acc[ni] = __builtin_amdgcn_mfma_f32_16x16x32_bf16(af, bfr[ni], acc[ni], 0, 0, 0);
        }
    }
#pragma unroll
    for (int ni = 0; ni < 4; ++ni)
#pragma unroll
        for (int r = 0; r < 4; ++r) {
            int o = (wr << 4) + (lg << 2) + r;
            int p = (hrow << 7) + (wc << 6) + (ni << 4) + lr;
            pbuf[(size_t)((cg << 5) + o) * HW + p] = acc[ni][r];
        }
}

// ---- per-(pixel,k): sum 4 partials; IDX = pixel-index*512 into ccT ---------
__global__ __launch_bounds__(256) void make_idx_k(const float* __restrict__ pbuf,
                                                  const float* __restrict__ pb,
                                                  int4* __restrict__ IDX,
                                                  float4* __restrict__ WT) {
    int t = blockIdx.x * 256 + threadIdx.x;
    if (t >= 9 * HW) return;
    int k = t >> 14, p = t & 16383;
    int h = p >> 7, w = p & 127;
    float ox = 0.f, oy = 0.f;
#pragma unroll
    for (int cg = 0; cg < 4; ++cg) {
        ox += pbuf[(size_t)((cg << 5) + k) * HW + p];
        oy += pbuf[(size_t)((cg << 5) + 9 + k) * HW + p];
    }
    float px = ox + pb[k]     + (float)(k / 3 - 1) + (float)(h + 1);
    float py = oy + pb[9 + k] + (float)(k % 3 - 1) + (float)(w + 1);
    float fx = floorf(px), fy = floorf(py);
    float x0 = fminf(fmaxf(fx,        0.f), 129.f);
    float x1 = fminf(fmaxf(fx + 1.0f, 0.f), 129.f);
    float y0 = fminf(fmaxf(fy,        0.f), 129.f);
    float y1 = fminf(fmaxf(fy + 1.0f, 0.f), 129.f);
    float pxc = fminf(fmaxf(px, 0.f), 129.f);
    float pyc = fminf(fmaxf(py, 0.f), 129.f);
    float gx0 = 1.0f + x0 - pxc, gx1 = 1.0f - x1 + pxc;
    float gy0 = 1.0f + y0 - pyc, gy1 = 1.0f - y1 + pyc;
    int ix0 = (int)x0, ix1 = (int)x1, iy0 = (int)y0, iy1 = (int)y1;
    IDX[t] = make_int4((ix0 * 130 + iy0) << 9, (ix1 * 130 + iy1) << 9,
                       (ix0 * 130 + iy1) << 9, (ix1 * 130 + iy0) << 9);
    WT[t]  = make_float4(gx0 * gy0, gx1 * gy1, gx0 * gy1, gx1 * gy0);
}

// ============ deformable contraction v6: coalesced gather + reg prefetch ====
// Lane remap: 8 adjacent lanes cover 128 contiguous bytes of ONE pixel's
// channel row (was: 64 lanes x 64 distinct 1KB-strided rows => 64 cache lines
// per load instr). Gather line-requests/chunk: 2048 -> 512. Flat 72-chunk loop
// register-prefetches chunk c+1 (A tile + 4 corners + IDX/WT at kt bounds)
// between the publish barrier and the MFMA phase, hiding L2 latency.
__global__ __launch_bounds__(512, 2) void fam5_k(
        const unsigned short* __restrict__ ccT,    // [130*130][512] bf16
        const unsigned short* __restrict__ dcwTh,  // [9][256][512] bf16
        const int4* __restrict__ IDX, const float4* __restrict__ WT,
        unsigned short* __restrict__ famh) {       // 256 bf16 planes PSH
    __shared__ __align__(16) unsigned short As[256][72];   // 36,864 B (o-major)
    __shared__ __align__(16) unsigned short Bs[64][72];    //  9,216 B (px-major)
    int b = blockIdx.x;                 // 256 blocks
    int xcd = b & 7, sl = b >> 3;       // 32 slots per XCD
    int nt = (xcd << 5) + sl;           // XCD owns 16 contiguous hrows
    int hrow = nt >> 1, pc0 = (nt & 1) << 6;
    int tid = threadIdx.x;
    int wv = tid >> 6, lane = tid & 63;
    int wo = wv >> 1, wp = wv & 1;      // o-quarter (64) x px-half (32)
    int lr = lane & 15, lg = lane >> 4;
    int pxg = tid >> 3, grp = tid & 7;  // staging: 64 px x 8 ch-groups of 8
    int p2 = (hrow << 7) + pc0 + pxg;   // this thread's gather pixel
    f32x4 acc[4][2];
#pragma unroll
    for (int i = 0; i < 4; ++i)
#pragma unroll
        for (int j = 0; j < 2; ++j) acc[i][j] = (f32x4){0.f, 0.f, 0.f, 0.f};

    // ---- prologue: load chunk 0 (kt=0, ks=0) into registers ----
    int4   idc = IDX[p2];
    float4 wtc = WT[p2];
    bf16x8 a0, a1, a2, a3, v0, v1, v2, v3;
    {
        const unsigned short* dwk = dcwTh;
        a0 = *(const bf16x8*)(dwk + (size_t)(pxg      ) * 512 + (grp << 3));
        a1 = *(const bf16x8*)(dwk + (size_t)(pxg +  64) * 512 + (grp << 3));
        a2 = *(const bf16x8*)(dwk + (size_t)(pxg + 128) * 512 + (grp << 3));
        a3 = *(const bf16x8*)(dwk + (size_t)(pxg + 192) * 512 + (grp << 3));
        int cb = grp << 3;
        v0 = *(const bf16x8*)(ccT + idc.x + cb);
        v1 = *(const bf16x8*)(ccT + idc.y + cb);
        v2 = *(const bf16x8*)(ccT + idc.z + cb);
        v3 = *(const bf16x8*)(ccT + idc.w + cb);
    }

    for (int c = 0; c < 72; ++c) {       // chunk = kt*8 + ks/64
        // 1. publish current chunk to LDS (A tile + weighted B gather)
        *(bf16x8*)&As[pxg      ][grp << 3] = a0;
        *(bf16x8*)&As[pxg +  64][grp << 3] = a1;
        *(bf16x8*)&As[pxg + 128][grp << 3] = a2;
        *(bf16x8*)&As[pxg + 192][grp << 3] = a3;
        {
            unsigned short pk[8];
#pragma unroll
            for (int e = 0; e < 8; ++e) {
                float val = wtc.x * bf2f((unsigned short)v0[e])
                          + wtc.y * bf2f((unsigned short)v1[e])
                          + wtc.z * bf2f((unsigned short)v2[e])
                          + wtc.w * bf2f((unsigned short)v3[e]);
                pk[e] = f2bf(val);
            }
            *(bf16x8*)&Bs[pxg][grp << 3] = *(bf16x8*)pk;
        }
        __syncthreads();

        // 2. prefetch chunk c+1 into registers (in flight during MFMA)
        int4   idn = idc;  float4 wtn = wtc;
        bf16x8 na0 = a0, na1 = a1, na2 = a2, na3 = a3;
        bf16x8 nv0 = v0, nv1 = v1, nv2 = v2, nv3 = v3;
        if (c < 71) {
            int cn  = c + 1;
            int ktn = cn >> 3, ksn = (cn & 7) << 6;
            if ((cn & 7) == 0) {
                idn = IDX[(ktn << 14) + p2];
                wtn = WT [(ktn << 14) + p2];
            }
            const unsigned short* dwk = dcwTh + (size_t)ktn * 131072 + ksn;
            na0 = *(const bf16x8*)(dwk + (size_t)(pxg      ) * 512 + (grp << 3));
            na1 = *(const bf16x8*)(dwk + (size_t)(pxg +  64) * 512 + (grp << 3));
            na2 = *(const bf16x8*)(dwk + (size_t)(pxg + 128) * 512 + (grp << 3));
            na3 = *(const bf16x8*)(dwk + (size_t)(pxg + 192) * 512 + (grp << 3));
            int cb = ksn + (grp << 3);
            nv0 = *(const bf16x8*)(ccT + idn.x + cb);
            nv1 = *(const bf16x8*)(ccT + idn.y + cb);
            nv2 = *(const bf16x8*)(ccT + idn.z + cb);
            nv3 = *(const bf16x8*)(ccT + idn.w + cb);
        }

        // 3. MFMA on the published LDS tiles
#pragma unroll
        for (int s = 0; s < 2; ++s) {
            int ko = (s << 5) + (lg << 3);
            bf16x8 af[4], bfr[2];
#pragma unroll
            for (int mi = 0; mi < 4; ++mi)
                af[mi] = *(const bf16x8*)(&As[(wo << 6) + (mi << 4) + lr][ko]);
#pragma unroll
            for (int ni = 0; ni < 2; ++ni)
                bfr[ni] = *(const bf16x8*)(&Bs[(wp << 5) + (ni << 4) + lr][ko]);
#pragma unroll
            for (int mi = 0; mi < 4; ++mi)
#pragma unroll
                for (int ni = 0; ni < 2; ++ni)
                    acc[mi][ni] = __builtin_amdgcn_mfma_f32_16x16x32_bf16(
                        af[mi], bfr[ni], acc[mi][ni], 0, 0, 0);
        }
        __syncthreads();

        // 4. rotate prefetched regs to current
        idc = idn; wtc = wtn;
        a0 = na0; a1 = na1; a2 = na2; a3 = na3;
        v0 = nv0; v1 = nv1; v2 = nv2; v3 = nv3;
    }
    size_t rowb = (size_t)(hrow + 1) * SH;
#pragma unroll
    for (int mi = 0; mi < 4; ++mi)
#pragma unroll
        for (int ni = 0; ni < 2; ++ni)
#pragma unroll
            for (int r = 0; r < 4; ++r) {
                int o   = (wo << 6) + (mi << 4) + (lg << 2) + r;
                int pxx = pc0 + (wp << 5) + (ni << 4) + lr;
                float cf = bf2f(ccT[(size_t)((hrow + 1) * 130 + pxx + 1) * 512 + 256 + o]);
                famh[(size_t)o * PSH + rowb + pxx + 1] = f2bf(acc[mi][ni][r] + cf);
            }
}

// ============ 3x3 conv 256->256: full-M 256o x 32px tiles + BN + ReLU =======
__global__ __launch_bounds__(256, 2) void conv2_k(
        const unsigned short* __restrict__ inh,   // 256 bf16 planes PSH, ring=0
        const unsigned short* __restrict__ wTh,   // [9][256][256] bf16
        const float* __restrict__ gam, const float* __restrict__ bet,
        const float* __restrict__ mean, const float* __restrict__ var,
        float* __restrict__ out_flat,             // [256][HW] f32
        unsigned short* __restrict__ out_padh) {  // optional bf16 planes
    __shared__ __align__(16) unsigned short Bs[32][40];
    __shared__ float scs[256], bis[256];
    int b = blockIdx.x;
    int xcd = b & 7, slot = b >> 3;
    int nt = (xcd << 6) + slot;
    int hrow = nt >> 2, pc0 = (nt & 3) << 5;
    int tid = threadIdx.x;
    int wv = tid >> 6, lane = tid & 63;
    int lr = lane & 15, lg = lane >> 4;
    int pxl = tid & 31, cg = tid >> 5;
    {
        float sc = gam[tid] * rsqrtf(var[tid] + 1e-5f);
        scs[tid] = sc;
        bis[tid] = bet[tid] - mean[tid] * sc;
    }
    f32x4 acc[4][2];
#pragma unroll
    for (int i = 0; i < 4; ++i)
#pragma unroll
        for (int j = 0; j < 2; ++j) acc[i][j] = (f32x4){0.f, 0.f, 0.f, 0.f};

    for (int kt = 0; kt < 9; ++kt) {
        int dy = kt / 3 - 1, dx = kt % 3 - 1;
        const unsigned short* src = inh + (size_t)(hrow + dy + 1) * SH + (pc0 + pxl + dx + 1);
        const unsigned short* wk  = wTh + (size_t)kt * 65536;
        for (int ks = 0; ks < 256; ks += 32) {
            __syncthreads();
            unsigned short pk[4];
#pragma unroll
            for (int e = 0; e < 4; ++e) {
                int c = ks + (cg << 2) + e;
                pk[e] = src[(size_t)c * PSH];
            }
            *(short4*)&Bs[pxl][cg << 2] = *(short4*)pk;
            __syncthreads();
            bf16x8 af[4], bfr[2];
#pragma unroll
            for (int mi = 0; mi < 4; ++mi) {
                int o = (wv << 6) + (mi << 4) + lr;
                af[mi] = *(const bf16x8*)(wk + (size_t)o * 256 + ks + (lg << 3));
            }
#pragma unroll
            for (int ni = 0; ni < 2; ++ni) {
                int n = (ni << 4) + lr;
                bfr[ni] = *(const bf16x8*)(&Bs[n][lg << 3]);
            }
#pragma unroll
            for (int mi = 0; mi < 4; ++mi)
#pragma unroll
                for (int ni = 0; ni < 2; ++ni)
                    acc[mi][ni] = __builtin_amdgcn_mfma_f32_16x16x32_bf16(
                        af[mi], bfr[ni], acc[mi][ni], 0, 0, 0);
        }
    }
    size_t rowb = (size_t)(hrow + 1) * SH;
#pragma unroll
    for (int mi = 0; mi < 4; ++mi)
#pragma unroll
        for (int ni = 0; ni < 2; ++ni)
#pragma unroll
            for (int r = 0; r < 4; ++r) {
                int o   = (wv << 6) + (mi << 4) + (lg << 2) + r;
                int pxx = pc0 + (ni << 4) + lr;
                float rv = fmaxf(acc[mi][ni][r] * scs[o] + bis[o], 0.0f);
                out_flat[(size_t)o * HW + (hrow << 7) + pxx] = rv;
                if (out_padh)
                    out_padh[(size_t)o * PSH + rowb + pxx + 1] = f2bf(rv);
            }
}

extern "C" void kernel_launch(void* const* d_in, const int* in_sizes, int n_in,
                              void* d_out, int out_size, void* d_ws, size_t ws_size,
                              hipStream_t stream) {
    const float* x     = (const float*)d_in[0];
    const float* llf   = (const float*)d_in[1];
    const float* fm_w  = (const float*)d_in[2];
    const float* fs_w  = (const float*)d_in[3];
    const float* p_w   = (const float*)d_in[4];
    const float* p_b   = (const float*)d_in[5];
    const float* dc_w  = (const float*)d_in[6];
    const float* lc1_w = (const float*)d_in[7];
    const float* bn1g  = (const float*)d_in[8];
    const float* bn1b  = (const float*)d_in[9];
    const float* bn1m  = (const float*)d_in[10];
    const float* bn1v  = (const float*)d_in[11];
    const float* lc2_w = (const float*)d_in[12];
    const float* bn2g  = (const float*)d_in[13];
    const float* bn2b  = (const float*)d_in[14];
    const float* bn2m  = (const float*)d_in[15];
    const float* bn2v  = (const float*)d_in[16];
    float* out1 = (float*)d_out;
    float* out2 = out1 + (size_t)256 * HW;

    // d_out is WRITE-ONLY (pure outputs). All scratch lives in ws.
    if (ws_size < 79839232u) return;
    char* ws = (char*)d_ws;
    unsigned short* ccT   = (unsigned short*)ws;                // [0, 17,305,600)
    float*          ccpad = (float*)(ws + 17305600);            // V region
    float*          vbuf  = (float*)(ws + 17305600);
    unsigned short* famh  = (unsigned short*)(ws + 17305600);
    unsigned short* up1h  = (unsigned short*)(ws + 26091520);
    unsigned short* llfT  = (unsigned short*)(ws + 34877440);
    unsigned short* uT    = (unsigned short*)(ws + 43266048);
    unsigned short* fmwh  = (unsigned short*)(ws + 51654656);   // 131,072
    unsigned short* fswh  = (unsigned short*)(ws + 51785728);   // 131,072
    float*          ubuf  = (float*)(ws + 51916800);            // U region
    float*          pbuf  = (float*)(ws + 51916800);
    int4*           IDX   = (int4*)  (ws + 60305408);
    float4*         WT    = (float4*)(ws + 62664704);
    unsigned short* dcwTh  = (unsigned short*)(ws + 68694016);  // 2,359,296
    unsigned short* lcw1Th = (unsigned short*)(ws + 71053312);  // 1,179,648
    unsigned short* lcw2Th = (unsigned short*)(ws + 72232960);  // 1,179,648
    unsigned short* pwTh   = (unsigned short*)(ws + 73412608);  //   294,912

    upsample_k<<<dim3(67, 256), 256, 0, stream>>>(x, ccpad);
    cvtT_k<<<dim3(16900), 256, 0, stream>>>(ccpad, ccT);          // ccpad dead after
    cvtT_flat_k<<<dim3(16384), 256, 0, stream>>>(llf, llfT, HW);
    w2bf_k<<<dim3(256), 256, 0, stream>>>(fm_w, fs_w, fmwh, fswh);
    vmfma_k<<<dim3(512), 256, 0, stream>>>(llfT, fmwh, vbuf);
    u_matmul_k<<<dim3(2, 256), 256, 0, stream>>>(llf, vbuf, ubuf);  // vbuf dead after
    cvtT_flat_k<<<dim3(16384), 256, 0, stream>>>(ubuf, uT, HW);   // ubuf dead after
    tr_ocK_k<<<dim3(4608), 256, 0, stream>>>(dc_w, dcwTh, 512);
    tr_ocK_k<<<dim3(2304), 256, 0, stream>>>(lc1_w, lcw1Th, 256);
    tr_ocK_k<<<dim3(2304), 256, 0, stream>>>(lc2_w, lcw2Th, 256);
    tr_pw_k<<<dim3(576), 256, 0, stream>>>(p_w, pwTh);
    cfmfma_k<<<dim3(512), 256, 0, stream>>>(uT, fswh, ccT);       // Cf -> ccT[:, 256:]
    ringT_k<<<dim3(520), 256, 0, stream>>>(ccT);                  // Cf ring = 0
    off_part_k<<<dim3(512), 256, 0, stream>>>(ccT, pwTh, pbuf);
    make_idx_k<<<dim3(576), 256, 0, stream>>>(pbuf, p_b, IDX, WT);
    zero_ring_h_k<<<dim3(521), 256, 0, stream>>>(famh, 256);
    zero_ring_h_k<<<dim3(521), 256, 0, stream>>>(up1h, 256);
    fam5_k<<<dim3(256), 512, 0, stream>>>(ccT, dcwTh, IDX, WT, famh);
    conv2_k<<<dim3(512), 256, 0, stream>>>(famh, lcw1Th, bn1g, bn1b, bn1m, bn1v,
                                           out1, up1h);
    conv2_k<<<dim3(512), 256, 0, stream>>>(up1h, lcw2Th, bn2g, bn2b, bn2m, bn2v,
                                           out2, nullptr);
}

// Round 2
// 529.920 us; speedup vs baseline: 1.1692x; 1.0254x over previous
//
#include <hip/hip_runtime.h>
#include <math.h>

#define HW   16384           // 128*128
#define PS   16900           // 130*130 f32 padded plane
#define PSH  17160           // 130*132 bf16 padded plane (stride 132)
#define SH   132

typedef __attribute__((ext_vector_type(8))) short bf16x8;
typedef __attribute__((ext_vector_type(4))) float f32x4;

__device__ inline unsigned short f2bf(float x) {
    unsigned int u = __float_as_uint(x);
    unsigned int r = (u + 0x7fffu + ((u >> 16) & 1u)) >> 16;
    return (unsigned short)r;
}
__device__ inline float bf2f(unsigned short h) {
    return __uint_as_float(((unsigned int)h) << 16);
}

// ---- zero the pad ring of nch bf16 padded planes (stride 132) --------------
__global__ __launch_bounds__(256) void zero_ring_h_k(unsigned short* __restrict__ base, int nch) {
    int t = blockIdx.x * 256 + threadIdx.x;
    if (t >= nch * 520) return;
    int ch = t / 520, rp = t - ch * 520;
    int row, col;
    if (rp < 132)      { row = 0;   col = rp; }
    else if (rp < 264) { row = 129; col = rp - 132; }
    else {
        int rem = rp - 264;
        if (rem >= 256) return;            // rows 1..128 only (no OOB spill)
        row = 1 + (rem >> 1); col = (rem & 1) ? 129 : 0;
    }
    base[(size_t)ch * PSH + row * SH + col] = 0;
}

// ---- zero ccT ring pixels for channels 256..511 (Cf) -----------------------
__global__ __launch_bounds__(256) void ringT_k(unsigned short* __restrict__ ccT) {
    int t = blockIdx.x * 256 + threadIdx.x;
    if (t >= 520 * 256) return;
    int ci = t & 255, rp = t >> 8;
    int row, col;
    if (rp < 130)      { row = 0;   col = rp; }
    else if (rp < 260) { row = 129; col = rp - 130; }
    else {
        int rem = rp - 260;
        if (rem >= 256) return;            // rows 1..128 only (no OOB spill)
        row = 1 + (rem >> 1); col = (rem & 1) ? 129 : 0;
    }
    ccT[(size_t)(row * 130 + col) * 512 + 256 + ci] = 0;
}

// ---- bilinear upsample (align_corners) 32x32 -> 128x128, into 256 f32 planes
__global__ __launch_bounds__(256) void upsample_k(const float* __restrict__ x,
                                                  float* __restrict__ ccpad) {
    int c = blockIdx.y;
    int idx = blockIdx.x * 256 + threadIdx.x;
    if (idx >= PS) return;
    int r = idx / 130, s = idx - r * 130;
    float val = 0.0f;
    if (r >= 1 && r <= 128 && s >= 1 && s <= 128) {
        int i = r - 1, j = s - 1;
        float yf = (float)i * (31.0f / 127.0f);
        float xf = (float)j * (31.0f / 127.0f);
        int y0 = min((int)yf, 31); int y1 = min(y0 + 1, 31);
        int x0 = min((int)xf, 31); int x1 = min(x0 + 1, 31);
        float wy = yf - (float)y0, wx = xf - (float)x0;
        const float* xc = x + (size_t)c * 1024;
        float a = xc[y0 * 32 + x0] * (1.0f - wx) + xc[y0 * 32 + x1] * wx;
        float b = xc[y1 * 32 + x0] * (1.0f - wx) + xc[y1 * 32 + x1] * wx;
        val = a * (1.0f - wy) + b * wy;
    }
    ccpad[(size_t)c * PS + idx] = val;
}

// ---- flat transpose+cvt: src f32 [256][npx] -> dst bf16 [npx][256] ---------
__global__ __launch_bounds__(256) void cvtT_flat_k(const float* __restrict__ src,
                                                   unsigned short* __restrict__ dst,
                                                   int npx) {
    int t = blockIdx.x * 256 + threadIdx.x;    // (pix, c), c fastest
    int c = t & 255, pix = t >> 8;
    dst[t] = f2bf(src[(size_t)c * npx + pix]);
}

// ---- ccpad f32 planes (256 ch, stride 130) -> ccT[pix][512] ch 0..255 ------
__global__ __launch_bounds__(256) void cvtT_k(const float* __restrict__ src,
                                              unsigned short* __restrict__ dst) {
    int t = blockIdx.x * 256 + threadIdx.x;    // 130*130*256 exactly
    int c = t & 255, pix = t >> 8;
    dst[(size_t)pix * 512 + c] = f2bf(src[(size_t)c * PS + pix]);
}

// ---- fm_w / fs_w (256x256 f32) -> bf16 -------------------------------------
__global__ __launch_bounds__(256) void w2bf_k(const float* __restrict__ a,
                                              const float* __restrict__ b,
                                              unsigned short* __restrict__ da,
                                              unsigned short* __restrict__ db) {
    int t = blockIdx.x * 256 + threadIdx.x;
    if (t >= 65536) return;
    da[t] = f2bf(a[t]);
    db[t] = f2bf(b[t]);
}

// ---- u[c,h,w] = sum_k L[c,h,k]*v[c,k,w] + L[c,h,w] (f32) -------------------
__global__ __launch_bounds__(256) void u_matmul_k(const float* __restrict__ llf,
                                                  const float* __restrict__ v,
                                                  float* __restrict__ u) {
    int c = blockIdx.y;
    const float* L = llf + (size_t)c * HW;
    const float* V = v   + (size_t)c * HW;
    float*       U = u   + (size_t)c * HW;
    int tid = threadIdx.x;
    int ty = tid >> 4, tx = tid & 15;
    int r0 = (blockIdx.x << 6) + (ty << 2);
    int w0 = tx << 3;
    float acc[4][8] = {};
    for (int k = 0; k < 128; ++k) {
        float a[4];
#pragma unroll
        for (int i = 0; i < 4; ++i) a[i] = L[(r0 + i) * 128 + k];
        float4 b0 = *(const float4*)(V + k * 128 + w0);
        float4 b1 = *(const float4*)(V + k * 128 + w0 + 4);
        float bv[8] = {b0.x, b0.y, b0.z, b0.w, b1.x, b1.y, b1.z, b1.w};
#pragma unroll
        for (int i = 0; i < 4; ++i)
#pragma unroll
            for (int j = 0; j < 8; ++j) acc[i][j] += a[i] * bv[j];
    }
#pragma unroll
    for (int i = 0; i < 4; ++i) {
#pragma unroll
        for (int j = 0; j < 8; ++j) acc[i][j] += L[(r0 + i) * 128 + w0 + j];
        *(float4*)(U + (r0 + i) * 128 + w0)     = make_float4(acc[i][0], acc[i][1], acc[i][2], acc[i][3]);
        *(float4*)(U + (r0 + i) * 128 + w0 + 4) = make_float4(acc[i][4], acc[i][5], acc[i][6], acc[i][7]);
    }
}

// ---- weights (O,C,3,3) f32 -> [k][o][c] bf16 (O=256) -----------------------
__global__ __launch_bounds__(256) void tr_ocK_k(const float* __restrict__ w,
                                                unsigned short* __restrict__ dst, int C) {
    int t = blockIdx.x * 256 + threadIdx.x;
    if (t >= 9 * 256 * C) return;
    int c = t % C; int rest = t / C; int o = rest & 255; int k = rest >> 8;
    dst[t] = f2bf(w[(size_t)o * C * 9 + c * 9 + k]);
}

// ---- p_w (18,512,3,3) f32 -> [k][32][512] bf16, zero-padded to 32 o --------
__global__ __launch_bounds__(256) void tr_pw_k(const float* __restrict__ w,
                                               unsigned short* __restrict__ dst) {
    int t = blockIdx.x * 256 + threadIdx.x;
    if (t >= 9 * 32 * 512) return;
    int c = t & 511; int rest = t >> 9; int o = rest & 31; int k = rest >> 5;
    dst[t] = (o < 18) ? f2bf(w[(size_t)o * 4608 + c * 9 + k]) : (unsigned short)0;
}

// ============ 1x1 GEMM (K=256) 256o x 32px MFMA + sigmoid -> f32 planes =====
__global__ __launch_bounds__(256, 2) void vmfma_k(
        const unsigned short* __restrict__ inT,   // [HW][256] bf16
        const unsigned short* __restrict__ wh,    // [256][256] bf16
        float* __restrict__ vout) {               // [256][HW] f32
    __shared__ __align__(16) unsigned short Bs[32][72];
    int b = blockIdx.x;
    int xcd = b & 7, sl = b >> 3;
    int nt = (xcd << 6) + sl;
    int hrow = nt >> 2, pc0 = (nt & 3) << 5;
    int tid = threadIdx.x;
    int wv = tid >> 6, lane = tid & 63;
    int lr = lane & 15, lg = lane >> 4;
    // staging map: 8 adjacent lanes cover 128 contiguous B of one pixel row
    int pxs = tid >> 3, cg8 = tid & 7;
    int p = (hrow << 7) + pc0 + pxs;
    f32x4 acc[4][2];
#pragma unroll
    for (int i = 0; i < 4; ++i)
#pragma unroll
        for (int j = 0; j < 2; ++j) acc[i][j] = (f32x4){0.f, 0.f, 0.f, 0.f};
    for (int ks = 0; ks < 256; ks += 64) {
        __syncthreads();
        *(bf16x8*)&Bs[pxs][cg8 << 3] =
            *(const bf16x8*)(inT + (size_t)p * 256 + ks + (cg8 << 3));
        __syncthreads();
#pragma unroll
        for (int s = 0; s < 2; ++s) {
            int ko = ks + (s << 5) + (lg << 3);
            bf16x8 af[4], bfr[2];
#pragma unroll
            for (int mi = 0; mi < 4; ++mi)
                af[mi] = *(const bf16x8*)(wh + (size_t)((wv << 6) + (mi << 4) + lr) * 256 + ko);
#pragma unroll
            for (int ni = 0; ni < 2; ++ni)
                bfr[ni] = *(const bf16x8*)(&Bs[(ni << 4) + lr][(s << 5) + (lg << 3)]);
#pragma unroll
            for (int mi = 0; mi < 4; ++mi)
#pragma unroll
                for (int ni = 0; ni < 2; ++ni)
                    acc[mi][ni] = __builtin_amdgcn_mfma_f32_16x16x32_bf16(
                        af[mi], bfr[ni], acc[mi][ni], 0, 0, 0);
        }
    }
#pragma unroll
    for (int mi = 0; mi < 4; ++mi)
#pragma unroll
        for (int ni = 0; ni < 2; ++ni)
#pragma unroll
            for (int r = 0; r < 4; ++r) {
                int o   = (wv << 6) + (mi << 4) + (lg << 2) + r;
                int pxx = pc0 + (ni << 4) + lr;
                vout[(size_t)o * HW + (hrow << 7) + pxx] =
                    1.0f / (1.0f + expf(-acc[mi][ni][r]));
            }
}

// ============ 1x1 GEMM (K=256) Cf -> ccT channels 256..511 ==================
__global__ __launch_bounds__(256, 2) void cfmfma_k(
        const unsigned short* __restrict__ inT,   // uT [HW][256] bf16
        const unsigned short* __restrict__ wh,    // fs_w [256][256] bf16
        unsigned short* __restrict__ ccT) {       // [130*130][512] bf16
    __shared__ __align__(16) unsigned short Bs[32][72];
    int b = blockIdx.x;
    int xcd = b & 7, sl = b >> 3;
    int nt = (xcd << 6) + sl;
    int hrow = nt >> 2, pc0 = (nt & 3) << 5;
    int tid = threadIdx.x;
    int wv = tid >> 6, lane = tid & 63;
    int lr = lane & 15, lg = lane >> 4;
    int pxs = tid >> 3, cg8 = tid & 7;
    int p = (hrow << 7) + pc0 + pxs;
    f32x4 acc[4][2];
#pragma unroll
    for (int i = 0; i < 4; ++i)
#pragma unroll
        for (int j = 0; j < 2; ++j) acc[i][j] = (f32x4){0.f, 0.f, 0.f, 0.f};
    for (int ks = 0; ks < 256; ks += 64) {
        __syncthreads();
        *(bf16x8*)&Bs[pxs][cg8 << 3] =
            *(const bf16x8*)(inT + (size_t)p * 256 + ks + (cg8 << 3));
        __syncthreads();
#pragma unroll
        for (int s = 0; s < 2; ++s) {
            int ko = ks + (s << 5) + (lg << 3);
            bf16x8 af[4], bfr[2];
#pragma unroll
            for (int mi = 0; mi < 4; ++mi)
                af[mi] = *(const bf16x8*)(wh + (size_t)((wv << 6) + (mi << 4) + lr) * 256 + ko);
#pragma unroll
            for (int ni = 0; ni < 2; ++ni)
                bfr[ni] = *(const bf16x8*)(&Bs[(ni << 4) + lr][(s << 5) + (lg << 3)]);
#pragma unroll
            for (int mi = 0; mi < 4; ++mi)
#pragma unroll
                for (int ni = 0; ni < 2; ++ni)
                    acc[mi][ni] = __builtin_amdgcn_mfma_f32_16x16x32_bf16(
                        af[mi], bfr[ni], acc[mi][ni], 0, 0, 0);
        }
    }
#pragma unroll
    for (int mi = 0; mi < 4; ++mi)
#pragma unroll
        for (int ni = 0; ni < 2; ++ni) {
            int pxx = pc0 + (ni << 4) + lr;
            int pix = (hrow + 1) * 130 + pxx + 1;
            unsigned short pk[4];
#pragma unroll
            for (int r = 0; r < 4; ++r) pk[r] = f2bf(acc[mi][ni][r]);
            *(ushort4*)(ccT + (size_t)pix * 512 + 256 + (wv << 6) + (mi << 4) + (lg << 2))
                = *(ushort4*)pk;
        }
}

// ============ offset conv 512->18: channel-split partials, ccT staging ======
__global__ __launch_bounds__(256, 2) void off_part_k(
        const unsigned short* __restrict__ ccT,   // [130*130][512] bf16
        const unsigned short* __restrict__ pwTh,  // [9][32][512] bf16
        float* __restrict__ pbuf) {               // [4][32][HW] f32
    __shared__ __align__(16) unsigned short Bs[128][40];
    int b = blockIdx.x;
    int xcd = b & 7, slot = b >> 3;               // 64 slots
    int hrow = (xcd << 4) + (slot >> 2);
    int cg = slot & 3, c0 = cg << 7;
    int tid = threadIdx.x;
    int wv = tid >> 6, lane = tid & 63;
    int wr = wv >> 1, wc = wv & 1;                // o-half(16) x px-half(64)
    int lr = lane & 15, lg = lane >> 4;
    // staging map: 4 adjacent lanes cover the full 64B ch-window of one pixel
    int c4 = tid & 3, pxs = tid >> 2;             // pxs in 0..63, 2 px passes
    f32x4 acc[4];
#pragma unroll
    for (int j = 0; j < 4; ++j) acc[j] = (f32x4){0.f, 0.f, 0.f, 0.f};

    for (int kt = 0; kt < 9; ++kt) {
        int dy = kt / 3 - 1, dx = kt % 3 - 1;
        int pixb = (hrow + dy + 1) * 130 + dx + 1;
        for (int ksl = 0; ksl < 128; ksl += 32) {
            __syncthreads();
#pragma unroll
            for (int pp = 0; pp < 2; ++pp) {
                int px = pxs + (pp << 6);
                *(bf16x8*)&Bs[px][c4 << 3] =
                    *(const bf16x8*)(ccT + (size_t)(pixb + px) * 512 + c0 + ksl + (c4 << 3));
            }
            __syncthreads();
            bf16x8 af, bfr[4];
            af = *(const bf16x8*)(pwTh + (size_t)kt * 16384
                                  + (size_t)((wr << 4) + lr) * 512 + c0 + ksl + (lg << 3));
#pragma unroll
            for (int ni = 0; ni < 4; ++ni) {
                int n = (wc << 6) + (ni << 4) + lr;
                bfr[ni] = *(const bf16x8*)(&Bs[n][lg << 3]);
            }
#pragma unroll
            for (int ni = 0; ni < 4; ++ni)
                acc[ni] = __builtin_amdgcn_mfma_f32_16x16x32_bf16(af, bfr[ni], acc[ni], 0, 0, 0);
        }
    }
#pragma unroll
    for (int ni = 0; ni < 4; ++ni)
#pragma unroll
        for (int r = 0; r < 4; ++r) {
            int o = (wr << 4) + (lg << 2) + r;
            int p = (hrow << 7) + (wc << 6) + (ni << 4) + lr;
            pbuf[(size_t)((cg << 5) + o) * HW + p] = acc[ni][r];
        }
}

// ---- per-(pixel,k): sum 4 partials; IDX = pixel-index*512 into ccT ---------
__global__ __launch_bounds__(256) void make_idx_k(const float* __restrict__ pbuf,
                                                  const float* __restrict__ pb,
                                                  int4* __restrict__ IDX,
                                                  float4* __restrict__ WT) {
    int t = blockIdx.x * 256 + threadIdx.x;
    if (t >= 9 * HW) return;
    int k = t >> 14, p = t & 16383;
    int h = p >> 7, w = p & 127;
    float ox = 0.f, oy = 0.f;
#pragma unroll
    for (int cg = 0; cg < 4; ++cg) {
        ox += pbuf[(size_t)((cg << 5) + k) * HW + p];
        oy += pbuf[(size_t)((cg << 5) + 9 + k) * HW + p];
    }
    float px = ox + pb[k]     + (float)(k / 3 - 1) + (float)(h + 1);
    float py = oy + pb[9 + k] + (float)(k % 3 - 1) + (float)(w + 1);
    float fx = floorf(px), fy = floorf(py);
    float x0 = fminf(fmaxf(fx,        0.f), 129.f);
    float x1 = fminf(fmaxf(fx + 1.0f, 0.f), 129.f);
    float y0 = fminf(fmaxf(fy,        0.f), 129.f);
    float y1 = fminf(fmaxf(fy + 1.0f, 0.f), 129.f);
    float pxc = fminf(fmaxf(px, 0.f), 129.f);
    float pyc = fminf(fmaxf(py, 0.f), 129.f);
    float gx0 = 1.0f + x0 - pxc, gx1 = 1.0f - x1 + pxc;
    float gy0 = 1.0f + y0 - pyc, gy1 = 1.0f - y1 + pyc;
    int ix0 = (int)x0, ix1 = (int)x1, iy0 = (int)y0, iy1 = (int)y1;
    IDX[t] = make_int4((ix0 * 130 + iy0) << 9, (ix1 * 130 + iy1) << 9,
                       (ix0 * 130 + iy1) << 9, (ix1 * 130 + iy0) << 9);
    WT[t]  = make_float4(gx0 * gy0, gx1 * gy1, gx0 * gy1, gx1 * gy0);
}

// ============ deformable contraction v7: 2-deep prefetch, 1 barrier/chunk ===
// Double-buffered LDS (As/Bs x2, 92KB) -> single barrier per chunk (buffer
// reuse is >=2 barriers apart). Two NAMED register sets (A/B) hold chunks c
// and c+1; chunk c+2's loads are issued while publishing chunk c, giving the
// gather ~2 chunk bodies (~1500 cyc) to land (covers L3). IDX/WT for kt+1
// are prefetched a full kt ahead (idc/idn), killing the dependent
// IDX-load -> gather-address chain at kt boundaries.
__global__ __launch_bounds__(512, 2) void fam6_k(
        const unsigned short* __restrict__ ccT,    // [130*130][512] bf16
        const unsigned short* __restrict__ dcwTh,  // [9][256][512] bf16
        const int4* __restrict__ IDX, const float4* __restrict__ WT,
        unsigned short* __restrict__ famh) {       // 256 bf16 planes PSH
    __shared__ __align__(16) unsigned short As[2][256][72];  // 73,728 B
    __shared__ __align__(16) unsigned short Bs[2][64][72];   // 18,432 B
    int b = blockIdx.x;                 // 256 blocks
    int xcd = b & 7, sl = b >> 3;       // 32 slots per XCD
    int nt = (xcd << 5) + sl;           // XCD owns 16 contiguous hrows
    int hrow = nt >> 1, pc0 = (nt & 1) << 6;
    int tid = threadIdx.x;
    int wv = tid >> 6, lane = tid & 63;
    int wo = wv >> 1, wp = wv & 1;      // o-quarter (64) x px-half (32)
    int lr = lane & 15, lg = lane >> 4;
    int pxg = tid >> 3, grp = tid & 7;  // staging: 64 px x 8 ch-groups of 8
    int p2 = (hrow << 7) + pc0 + pxg;   // this thread's gather pixel
    f32x4 acc[4][2];
#pragma unroll
    for (int i = 0; i < 4; ++i)
#pragma unroll
        for (int j = 0; j < 2; ++j) acc[i][j] = (f32x4){0.f, 0.f, 0.f, 0.f};

#define ISSUEM(S, ktm, ksn, idm, wtm) do {                                    \
    const unsigned short* dwk_ = dcwTh + (size_t)(ktm) * 131072 + (ksn);      \
    S##a0 = *(const bf16x8*)(dwk_ + (size_t)(pxg      ) * 512 + (grp << 3));  \
    S##a1 = *(const bf16x8*)(dwk_ + (size_t)(pxg +  64) * 512 + (grp << 3));  \
    S##a2 = *(const bf16x8*)(dwk_ + (size_t)(pxg + 128) * 512 + (grp << 3));  \
    S##a3 = *(const bf16x8*)(dwk_ + (size_t)(pxg + 192) * 512 + (grp << 3));  \
    int cb_ = (ksn) + (grp << 3);                                             \
    S##v0 = *(const bf16x8*)(ccT + (idm).x + cb_);                            \
    S##v1 = *(const bf16x8*)(ccT + (idm).y + cb_);                            \
    S##v2 = *(const bf16x8*)(ccT + (idm).z + cb_);                            \
    S##v3 = *(const bf16x8*)(ccT + (idm).w + cb_);                            \
    S##wt = (wtm);                                                            \
} while (0)

#define PUBLISHM(S, bi) do {                                                  \
    *(bf16x8*)&As[bi][pxg      ][grp << 3] = S##a0;                           \
    *(bf16x8*)&As[bi][pxg +  64][grp << 3] = S##a1;                           \
    *(bf16x8*)&As[bi][pxg + 128][grp << 3] = S##a2;                           \
    *(bf16x8*)&As[bi][pxg + 192][grp << 3] = S##a3;                           \
    unsigned short pk_[8];                                                    \
    _Pragma("unroll")                                                         \
    for (int e_ = 0; e_ < 8; ++e_) {                                          \
        float val_ = S##wt.x * bf2f((unsigned short)S##v0[e_])                \
                   + S##wt.y * bf2f((unsigned short)S##v1[e_])                \
                   + S##wt.z * bf2f((unsigned short)S##v2[e_])                \
                   + S##wt.w * bf2f((unsigned short)S##v3[e_]);               \
        pk_[e_] = f2bf(val_);                                                 \
    }                                                                         \
    *(bf16x8*)&Bs[bi][pxg][grp << 3] = *(bf16x8*)pk_;                         \
} while (0)

#define MFMAM(bi) do {                                                        \
    _Pragma("unroll")                                                         \
    for (int s_ = 0; s_ < 2; ++s_) {                                          \
        int ko_ = (s_ << 5) + (lg << 3);                                      \
        bf16x8 af_[4], bf_[2];                                                \
        _Pragma("unroll")                                                     \
        for (int mi_ = 0; mi_ < 4; ++mi_)                                     \
            af_[mi_] = *(const bf16x8*)(&As[bi][(wo << 6) + (mi_ << 4) + lr][ko_]); \
        _Pragma("unroll")                                                     \
        for (int ni_ = 0; ni_ < 2; ++ni_)                                     \
            bf_[ni_] = *(const bf16x8*)(&Bs[bi][(wp << 5) + (ni_ << 4) + lr][ko_]); \
        _Pragma("unroll")                                                     \
        for (int mi_ = 0; mi_ < 4; ++mi_)                                     \
            _Pragma("unroll")                                                 \
            for (int ni_ = 0; ni_ < 2; ++ni_)                                 \
                acc[mi_][ni_] = __builtin_amdgcn_mfma_f32_16x16x32_bf16(      \
                    af_[mi_], bf_[ni_], acc[mi_][ni_], 0, 0, 0);              \
    }                                                                         \
} while (0)

    // regsets: A holds even chunks, B holds odd chunks (static names, no
    // runtime-indexed arrays -> everything stays in VGPRs)
    bf16x8 Aa0, Aa1, Aa2, Aa3, Av0, Av1, Av2, Av3; float4 Awt;
    bf16x8 Ba0, Ba1, Ba2, Ba3, Bv0, Bv1, Bv2, Bv3; float4 Bwt;

    int4   idc = IDX[p2];
    float4 wtc = WT[p2];
    ISSUEM(A, 0, 0, idc, wtc);    // chunk 0
    ISSUEM(B, 0, 64, idc, wtc);   // chunk 1
    int4   idn = IDX[(1 << 14) + p2];
    float4 wtn = WT[(1 << 14) + p2];

    for (int kt = 0; kt < 9; ++kt) {
        // j=0: publish chunk kt*8+0, issue kt*8+2
        PUBLISHM(A, 0); ISSUEM(A, kt, 128, idc, wtc); __syncthreads(); MFMAM(0);
        // j=1
        PUBLISHM(B, 1); ISSUEM(B, kt, 192, idc, wtc); __syncthreads(); MFMAM(1);
        // j=2
        PUBLISHM(A, 0); ISSUEM(A, kt, 256, idc, wtc); __syncthreads(); MFMAM(0);
        // j=3
        PUBLISHM(B, 1); ISSUEM(B, kt, 320, idc, wtc); __syncthreads(); MFMAM(1);
        // j=4
        PUBLISHM(A, 0); ISSUEM(A, kt, 384, idc, wtc); __syncthreads(); MFMAM(0);
        // j=5
        PUBLISHM(B, 1); ISSUEM(B, kt, 448, idc, wtc); __syncthreads(); MFMAM(1);
        // j=6: issue crosses into kt+1 (chunk (kt+1)*8+0), uses idn/wtn
        PUBLISHM(A, 0);
        if (kt < 8) ISSUEM(A, kt + 1, 0, idn, wtn);
        __syncthreads(); MFMAM(0);
        // j=7: issue chunk (kt+1)*8+1
        PUBLISHM(B, 1);
        if (kt < 8) ISSUEM(B, kt + 1, 64, idn, wtn);
        __syncthreads(); MFMAM(1);
        // rotate kt-level IDX/WT; prefetch kt+2's a full kt ahead
        idc = idn; wtc = wtn;
        if (kt < 7) {
            idn = IDX[((kt + 2) << 14) + p2];
            wtn = WT[((kt + 2) << 14) + p2];
        }
    }
#undef ISSUEM
#undef PUBLISHM
#undef MFMAM

    size_t rowb = (size_t)(hrow + 1) * SH;
#pragma unroll
    for (int mi = 0; mi < 4; ++mi)
#pragma unroll
        for (int ni = 0; ni < 2; ++ni)
#pragma unroll
            for (int r = 0; r < 4; ++r) {
                int o   = (wo << 6) + (mi << 4) + (lg << 2) + r;
                int pxx = pc0 + (wp << 5) + (ni << 4) + lr;
                float cf = bf2f(ccT[(size_t)((hrow + 1) * 130 + pxx + 1) * 512 + 256 + o]);
                famh[(size_t)o * PSH + rowb + pxx + 1] = f2bf(acc[mi][ni][r] + cf);
            }
}

// ============ 3x3 conv 256->256: full-M 256o x 32px tiles + BN + ReLU =======
__global__ __launch_bounds__(256, 2) void conv2_k(
        const unsigned short* __restrict__ inh,   // 256 bf16 planes PSH, ring=0
        const unsigned short* __restrict__ wTh,   // [9][256][256] bf16
        const float* __restrict__ gam, const float* __restrict__ bet,
        const float* __restrict__ mean, const float* __restrict__ var,
        float* __restrict__ out_flat,             // [256][HW] f32
        unsigned short* __restrict__ out_padh) {  // optional bf16 planes
    __shared__ __align__(16) unsigned short Bs[32][40];
    __shared__ float scs[256], bis[256];
    int b = blockIdx.x;
    int xcd = b & 7, slot = b >> 3;
    int nt = (xcd << 6) + slot;
    int hrow = nt >> 2, pc0 = (nt & 3) << 5;
    int tid = threadIdx.x;
    int wv = tid >> 6, lane = tid & 63;
    int lr = lane & 15, lg = lane >> 4;
    int pxl = tid & 31, cg = tid >> 5;
    {
        float sc = gam[tid] * rsqrtf(var[tid] + 1e-5f);
        scs[tid] = sc;
        bis[tid] = bet[tid] - mean[tid] * sc;
    }
    f32x4 acc[4][2];
#pragma unroll
    for (int i = 0; i < 4; ++i)
#pragma unroll
        for (int j = 0; j < 2; ++j) acc[i][j] = (f32x4){0.f, 0.f, 0.f, 0.f};

    for (int kt = 0; kt < 9; ++kt) {
        int dy = kt / 3 - 1, dx = kt % 3 - 1;
        const unsigned short* src = inh + (size_t)(hrow + dy + 1) * SH + (pc0 + pxl + dx + 1);
        const unsigned short* wk  = wTh + (size_t)kt * 65536;
        for (int ks = 0; ks < 256; ks += 32) {
            __syncthreads();
            unsigned short pk[4];
#pragma unroll
            for (int e = 0; e < 4; ++e) {
                int c = ks + (cg << 2) + e;
                pk[e] = src[(size_t)c * PSH];
            }
            *(short4*)&Bs[pxl][cg << 2] = *(short4*)pk;
            __syncthreads();
            bf16x8 af[4], bfr[2];
#pragma unroll
            for (int mi = 0; mi < 4; ++mi) {
                int o = (wv << 6) + (mi << 4) + lr;
                af[mi] = *(const bf16x8*)(wk + (size_t)o * 256 + ks + (lg << 3));
            }
#pragma unroll
            for (int ni = 0; ni < 2; ++ni) {
                int n = (ni << 4) + lr;
                bfr[ni] = *(const bf16x8*)(&Bs[n][lg << 3]);
            }
#pragma unroll
            for (int mi = 0; mi < 4; ++mi)
#pragma unroll
                for (int ni = 0; ni < 2; ++ni)
                    acc[mi][ni] = __builtin_amdgcn_mfma_f32_16x16x32_bf16(
                        af[mi], bfr[ni], acc[mi][ni], 0, 0, 0);
        }
    }
    size_t rowb = (size_t)(hrow + 1) * SH;
#pragma unroll
    for (int mi = 0; mi < 4; ++mi)
#pragma unroll
        for (int ni = 0; ni < 2; ++ni)
#pragma unroll
            for (int r = 0; r < 4; ++r) {
                int o   = (wv << 6) + (mi << 4) + (lg << 2) + r;
                int pxx = pc0 + (ni << 4) + lr;
                float rv = fmaxf(acc[mi][ni][r] * scs[o] + bis[o], 0.0f);
                out_flat[(size_t)o * HW + (hrow << 7) + pxx] = rv;
                if (out_padh)
                    out_padh[(size_t)o * PSH + rowb + pxx + 1] = f2bf(rv);
            }
}

extern "C" void kernel_launch(void* const* d_in, const int* in_sizes, int n_in,
                              void* d_out, int out_size, void* d_ws, size_t ws_size,
                              hipStream_t stream) {
    const float* x     = (const float*)d_in[0];
    const float* llf   = (const float*)d_in[1];
    const float* fm_w  = (const float*)d_in[2];
    const float* fs_w  = (const float*)d_in[3];
    const float* p_w   = (const float*)d_in[4];
    const float* p_b   = (const float*)d_in[5];
    const float* dc_w  = (const float*)d_in[6];
    const float* lc1_w = (const float*)d_in[7];
    const float* bn1g  = (const float*)d_in[8];
    const float* bn1b  = (const float*)d_in[9];
    const float* bn1m  = (const float*)d_in[10];
    const float* bn1v  = (const float*)d_in[11];
    const float* lc2_w = (const float*)d_in[12];
    const float* bn2g  = (const float*)d_in[13];
    const float* bn2b  = (const float*)d_in[14];
    const float* bn2m  = (const float*)d_in[15];
    const float* bn2v  = (const float*)d_in[16];
    float* out1 = (float*)d_out;
    float* out2 = out1 + (size_t)256 * HW;

    // d_out is WRITE-ONLY (pure outputs). All scratch lives in ws.
    if (ws_size < 79839232u) return;
    char* ws = (char*)d_ws;
    unsigned short* ccT   = (unsigned short*)ws;                // [0, 17,305,600)
    float*          ccpad = (float*)(ws + 17305600);            // V region
    float*          vbuf  = (float*)(ws + 17305600);
    unsigned short* famh  = (unsigned short*)(ws + 17305600);
    unsigned short* up1h  = (unsigned short*)(ws + 26091520);
    unsigned short* llfT  = (unsigned short*)(ws + 34877440);
    unsigned short* uT    = (unsigned short*)(ws + 43266048);
    unsigned short* fmwh  = (unsigned short*)(ws + 51654656);   // 131,072
    unsigned short* fswh  = (unsigned short*)(ws + 51785728);   // 131,072
    float*          ubuf  = (float*)(ws + 51916800);            // U region
    float*          pbuf  = (float*)(ws + 51916800);
    int4*           IDX   = (int4*)  (ws + 60305408);
    float4*         WT    = (float4*)(ws + 62664704);
    unsigned short* dcwTh  = (unsigned short*)(ws + 68694016);  // 2,359,296
    unsigned short* lcw1Th = (unsigned short*)(ws + 71053312);  // 1,179,648
    unsigned short* lcw2Th = (unsigned short*)(ws + 72232960);  // 1,179,648
    unsigned short* pwTh   = (unsigned short*)(ws + 73412608);  //   294,912

    upsample_k<<<dim3(67, 256), 256, 0, stream>>>(x, ccpad);
    cvtT_k<<<dim3(16900), 256, 0, stream>>>(ccpad, ccT);          // ccpad dead after
    cvtT_flat_k<<<dim3(16384), 256, 0, stream>>>(llf, llfT, HW);
    w2bf_k<<<dim3(256), 256, 0, stream>>>(fm_w, fs_w, fmwh, fswh);
    vmfma_k<<<dim3(512), 256, 0, stream>>>(llfT, fmwh, vbuf);
    u_matmul_k<<<dim3(2, 256), 256, 0, stream>>>(llf, vbuf, ubuf);  // vbuf dead after
    cvtT_flat_k<<<dim3(16384), 256, 0, stream>>>(ubuf, uT, HW);   // ubuf dead after
    tr_ocK_k<<<dim3(4608), 256, 0, stream>>>(dc_w, dcwTh, 512);
    tr_ocK_k<<<dim3(2304), 256, 0, stream>>>(lc1_w, lcw1Th, 256);
    tr_ocK_k<<<dim3(2304), 256, 0, stream>>>(lc2_w, lcw2Th, 256);
    tr_pw_k<<<dim3(576), 256, 0, stream>>>(p_w, pwTh);
    cfmfma_k<<<dim3(512), 256, 0, stream>>>(uT, fswh, ccT);       // Cf -> ccT[:, 256:]
    ringT_k<<<dim3(520), 256, 0, stream>>>(ccT);                  // Cf ring = 0
    off_part_k<<<dim3(512), 256, 0, stream>>>(ccT, pwTh, pbuf);
    make_idx_k<<<dim3(576), 256, 0, stream>>>(pbuf, p_b, IDX, WT);
    zero_ring_h_k<<<dim3(521), 256, 0, stream>>>(famh, 256);
    zero_ring_h_k<<<dim3(521), 256, 0, stream>>>(up1h, 256);
    fam6_k<<<dim3(256), 512, 0, stream>>>(ccT, dcwTh, IDX, WT, famh);
    conv2_k<<<dim3(512), 256, 0, stream>>>(famh, lcw1Th, bn1g, bn1b, bn1m, bn1v,
                                           out1, up1h);
    conv2_k<<<dim3(512), 256, 0, stream>>>(up1h, lcw2Th, bn2g, bn2b, bn2m, bn2v,
                                           out2, nullptr);
}

// Round 3
// 527.649 us; speedup vs baseline: 1.1743x; 1.0043x over previous
//
#include <hip/hip_runtime.h>
#include <math.h>

#define HW   16384           // 128*128
#define PS   16900           // 130*130 f32 padded plane
#define PSH  17160           // 130*132 bf16 padded plane (stride 132)
#define SH   132

typedef __attribute__((ext_vector_type(8))) short bf16x8;
typedef __attribute__((ext_vector_type(4))) float f32x4;

__device__ inline unsigned short f2bf(float x) {
    unsigned int u = __float_as_uint(x);
    unsigned int r = (u + 0x7fffu + ((u >> 16) & 1u)) >> 16;
    return (unsigned short)r;
}
__device__ inline float bf2f(unsigned short h) {
    return __uint_as_float(((unsigned int)h) << 16);
}

// ---- zero the pad ring of nch bf16 padded planes (stride 132) --------------
__global__ __launch_bounds__(256) void zero_ring_h_k(unsigned short* __restrict__ base, int nch) {
    int t = blockIdx.x * 256 + threadIdx.x;
    if (t >= nch * 520) return;
    int ch = t / 520, rp = t - ch * 520;
    int row, col;
    if (rp < 132)      { row = 0;   col = rp; }
    else if (rp < 264) { row = 129; col = rp - 132; }
    else {
        int rem = rp - 264;
        if (rem >= 256) return;            // rows 1..128 only (no OOB spill)
        row = 1 + (rem >> 1); col = (rem & 1) ? 129 : 0;
    }
    base[(size_t)ch * PSH + row * SH + col] = 0;
}

// ---- zero ccT ring pixels for channels 256..511 (Cf) -----------------------
__global__ __launch_bounds__(256) void ringT_k(unsigned short* __restrict__ ccT) {
    int t = blockIdx.x * 256 + threadIdx.x;
    if (t >= 520 * 256) return;
    int ci = t & 255, rp = t >> 8;
    int row, col;
    if (rp < 130)      { row = 0;   col = rp; }
    else if (rp < 260) { row = 129; col = rp - 130; }
    else {
        int rem = rp - 260;
        if (rem >= 256) return;            // rows 1..128 only (no OOB spill)
        row = 1 + (rem >> 1); col = (rem & 1) ? 129 : 0;
    }
    ccT[(size_t)(row * 130 + col) * 512 + 256 + ci] = 0;
}

// ---- bilinear upsample (align_corners) 32x32 -> 128x128, into 256 f32 planes
__global__ __launch_bounds__(256) void upsample_k(const float* __restrict__ x,
                                                  float* __restrict__ ccpad) {
    int c = blockIdx.y;
    int idx = blockIdx.x * 256 + threadIdx.x;
    if (idx >= PS) return;
    int r = idx / 130, s = idx - r * 130;
    float val = 0.0f;
    if (r >= 1 && r <= 128 && s >= 1 && s <= 128) {
        int i = r - 1, j = s - 1;
        float yf = (float)i * (31.0f / 127.0f);
        float xf = (float)j * (31.0f / 127.0f);
        int y0 = min((int)yf, 31); int y1 = min(y0 + 1, 31);
        int x0 = min((int)xf, 31); int x1 = min(x0 + 1, 31);
        float wy = yf - (float)y0, wx = xf - (float)x0;
        const float* xc = x + (size_t)c * 1024;
        float a = xc[y0 * 32 + x0] * (1.0f - wx) + xc[y0 * 32 + x1] * wx;
        float b = xc[y1 * 32 + x0] * (1.0f - wx) + xc[y1 * 32 + x1] * wx;
        val = a * (1.0f - wy) + b * wy;
    }
    ccpad[(size_t)c * PS + idx] = val;
}

// ---- flat transpose+cvt: src f32 [256][npx] -> dst bf16 [npx][256] ---------
__global__ __launch_bounds__(256) void cvtT_flat_k(const float* __restrict__ src,
                                                   unsigned short* __restrict__ dst,
                                                   int npx) {
    int t = blockIdx.x * 256 + threadIdx.x;    // (pix, c), c fastest
    int c = t & 255, pix = t >> 8;
    dst[t] = f2bf(src[(size_t)c * npx + pix]);
}

// ---- ccpad f32 planes (256 ch, stride 130) -> ccT[pix][512] ch 0..255 ------
__global__ __launch_bounds__(256) void cvtT_k(const float* __restrict__ src,
                                              unsigned short* __restrict__ dst) {
    int t = blockIdx.x * 256 + threadIdx.x;    // 130*130*256 exactly
    int c = t & 255, pix = t >> 8;
    dst[(size_t)pix * 512 + c] = f2bf(src[(size_t)c * PS + pix]);
}

// ---- fm_w / fs_w (256x256 f32) -> bf16 -------------------------------------
__global__ __launch_bounds__(256) void w2bf_k(const float* __restrict__ a,
                                              const float* __restrict__ b,
                                              unsigned short* __restrict__ da,
                                              unsigned short* __restrict__ db) {
    int t = blockIdx.x * 256 + threadIdx.x;
    if (t >= 65536) return;
    da[t] = f2bf(a[t]);
    db[t] = f2bf(b[t]);
}

// ---- u[c,h,w] = sum_k L[c,h,k]*v[c,k,w] + L[c,h,w] (f32) -------------------
__global__ __launch_bounds__(256) void u_matmul_k(const float* __restrict__ llf,
                                                  const float* __restrict__ v,
                                                  float* __restrict__ u) {
    int c = blockIdx.y;
    const float* L = llf + (size_t)c * HW;
    const float* V = v   + (size_t)c * HW;
    float*       U = u   + (size_t)c * HW;
    int tid = threadIdx.x;
    int ty = tid >> 4, tx = tid & 15;
    int r0 = (blockIdx.x << 6) + (ty << 2);
    int w0 = tx << 3;
    float acc[4][8] = {};
    for (int k = 0; k < 128; ++k) {
        float a[4];
#pragma unroll
        for (int i = 0; i < 4; ++i) a[i] = L[(r0 + i) * 128 + k];
        float4 b0 = *(const float4*)(V + k * 128 + w0);
        float4 b1 = *(const float4*)(V + k * 128 + w0 + 4);
        float bv[8] = {b0.x, b0.y, b0.z, b0.w, b1.x, b1.y, b1.z, b1.w};
#pragma unroll
        for (int i = 0; i < 4; ++i)
#pragma unroll
            for (int j = 0; j < 8; ++j) acc[i][j] += a[i] * bv[j];
    }
#pragma unroll
    for (int i = 0; i < 4; ++i) {
#pragma unroll
        for (int j = 0; j < 8; ++j) acc[i][j] += L[(r0 + i) * 128 + w0 + j];
        *(float4*)(U + (r0 + i) * 128 + w0)     = make_float4(acc[i][0], acc[i][1], acc[i][2], acc[i][3]);
        *(float4*)(U + (r0 + i) * 128 + w0 + 4) = make_float4(acc[i][4], acc[i][5], acc[i][6], acc[i][7]);
    }
}

// ---- weights (O,C,3,3) f32 -> [k][o][c] bf16 (O=256) -----------------------
__global__ __launch_bounds__(256) void tr_ocK_k(const float* __restrict__ w,
                                                unsigned short* __restrict__ dst, int C) {
    int t = blockIdx.x * 256 + threadIdx.x;
    if (t >= 9 * 256 * C) return;
    int c = t % C; int rest = t / C; int o = rest & 255; int k = rest >> 8;
    dst[t] = f2bf(w[(size_t)o * C * 9 + c * 9 + k]);
}

// ---- dc_w (256,512,3,3) f32 -> MFMA-fragment-major bf16 --------------------
// layout: [chunk=kt*8+ks64][wo(4)][frag=mi*2+s(8)][lane(64)][e(8)]
// so a wave's af load for (chunk,wo,mi,s) is 64 lanes x 16B contiguous (1KB).
__global__ __launch_bounds__(256) void tr_dcwF_k(const float* __restrict__ w,
                                                 unsigned short* __restrict__ dst) {
    int t = blockIdx.x * 256 + threadIdx.x;
    if (t >= 1179648) return;                 // 9*8*4*8*64*8
    int e    = t & 7;
    int lane = (t >> 3) & 63;
    int s    = (t >> 9) & 1;
    int mi   = (t >> 10) & 3;
    int wo   = (t >> 12) & 3;
    int ks64 = (t >> 14) & 7;
    int kt   = t >> 17;
    int o = (wo << 6) + (mi << 4) + (lane & 15);
    int c = (ks64 << 6) + (s << 5) + (((lane >> 4) & 3) << 3) + e;
    dst[t] = f2bf(w[(size_t)o * 4608 + c * 9 + kt]);
}

// ---- p_w (18,512,3,3) f32 -> [k][32][512] bf16, zero-padded to 32 o --------
__global__ __launch_bounds__(256) void tr_pw_k(const float* __restrict__ w,
                                               unsigned short* __restrict__ dst) {
    int t = blockIdx.x * 256 + threadIdx.x;
    if (t >= 9 * 32 * 512) return;
    int c = t & 511; int rest = t >> 9; int o = rest & 31; int k = rest >> 5;
    dst[t] = (o < 18) ? f2bf(w[(size_t)o * 4608 + c * 9 + k]) : (unsigned short)0;
}

// ============ 1x1 GEMM (K=256) 256o x 32px MFMA + sigmoid -> f32 planes =====
__global__ __launch_bounds__(256, 2) void vmfma_k(
        const unsigned short* __restrict__ inT,   // [HW][256] bf16
        const unsigned short* __restrict__ wh,    // [256][256] bf16
        float* __restrict__ vout) {               // [256][HW] f32
    __shared__ __align__(16) unsigned short Bs[32][72];
    int b = blockIdx.x;
    int xcd = b & 7, sl = b >> 3;
    int nt = (xcd << 6) + sl;
    int hrow = nt >> 2, pc0 = (nt & 3) << 5;
    int tid = threadIdx.x;
    int wv = tid >> 6, lane = tid & 63;
    int lr = lane & 15, lg = lane >> 4;
    // staging map: 8 adjacent lanes cover 128 contiguous B of one pixel row
    int pxs = tid >> 3, cg8 = tid & 7;
    int p = (hrow << 7) + pc0 + pxs;
    f32x4 acc[4][2];
#pragma unroll
    for (int i = 0; i < 4; ++i)
#pragma unroll
        for (int j = 0; j < 2; ++j) acc[i][j] = (f32x4){0.f, 0.f, 0.f, 0.f};
    for (int ks = 0; ks < 256; ks += 64) {
        __syncthreads();
        *(bf16x8*)&Bs[pxs][cg8 << 3] =
            *(const bf16x8*)(inT + (size_t)p * 256 + ks + (cg8 << 3));
        __syncthreads();
#pragma unroll
        for (int s = 0; s < 2; ++s) {
            int ko = ks + (s << 5) + (lg << 3);
            bf16x8 af[4], bfr[2];
#pragma unroll
            for (int mi = 0; mi < 4; ++mi)
                af[mi] = *(const bf16x8*)(wh + (size_t)((wv << 6) + (mi << 4) + lr) * 256 + ko);
#pragma unroll
            for (int ni = 0; ni < 2; ++ni)
                bfr[ni] = *(const bf16x8*)(&Bs[(ni << 4) + lr][(s << 5) + (lg << 3)]);
#pragma unroll
            for (int mi = 0; mi < 4; ++mi)
#pragma unroll
                for (int ni = 0; ni < 2; ++ni)
                    acc[mi][ni] = __builtin_amdgcn_mfma_f32_16x16x32_bf16(
                        af[mi], bfr[ni], acc[mi][ni], 0, 0, 0);
        }
    }
#pragma unroll
    for (int mi = 0; mi < 4; ++mi)
#pragma unroll
        for (int ni = 0; ni < 2; ++ni)
#pragma unroll
            for (int r = 0; r < 4; ++r) {
                int o   = (wv << 6) + (mi << 4) + (lg << 2) + r;
                int pxx = pc0 + (ni << 4) + lr;
                vout[(size_t)o * HW + (hrow << 7) + pxx] =
                    1.0f / (1.0f + expf(-acc[mi][ni][r]));
            }
}

// ============ 1x1 GEMM (K=256) Cf -> ccT channels 256..511 ==================
__global__ __launch_bounds__(256, 2) void cfmfma_k(
        const unsigned short* __restrict__ inT,   // uT [HW][256] bf16
        const unsigned short* __restrict__ wh,    // fs_w [256][256] bf16
        unsigned short* __restrict__ ccT) {       // [130*130][512] bf16
    __shared__ __align__(16) unsigned short Bs[32][72];
    int b = blockIdx.x;
    int xcd = b & 7, sl = b >> 3;
    int nt = (xcd << 6) + sl;
    int hrow = nt >> 2, pc0 = (nt & 3) << 5;
    int tid = threadIdx.x;
    int wv = tid >> 6, lane = tid & 63;
    int lr = lane & 15, lg = lane >> 4;
    int pxs = tid >> 3, cg8 = tid & 7;
    int p = (hrow << 7) + pc0 + pxs;
    f32x4 acc[4][2];
#pragma unroll
    for (int i = 0; i < 4; ++i)
#pragma unroll
        for (int j = 0; j < 2; ++j) acc[i][j] = (f32x4){0.f, 0.f, 0.f, 0.f};
    for (int ks = 0; ks < 256; ks += 64) {
        __syncthreads();
        *(bf16x8*)&Bs[pxs][cg8 << 3] =
            *(const bf16x8*)(inT + (size_t)p * 256 + ks + (cg8 << 3));
        __syncthreads();
#pragma unroll
        for (int s = 0; s < 2; ++s) {
            int ko = ks + (s << 5) + (lg << 3);
            bf16x8 af[4], bfr[2];
#pragma unroll
            for (int mi = 0; mi < 4; ++mi)
                af[mi] = *(const bf16x8*)(wh + (size_t)((wv << 6) + (mi << 4) + lr) * 256 + ko);
#pragma unroll
            for (int ni = 0; ni < 2; ++ni)
                bfr[ni] = *(const bf16x8*)(&Bs[(ni << 4) + lr][(s << 5) + (lg << 3)]);
#pragma unroll
            for (int mi = 0; mi < 4; ++mi)
#pragma unroll
                for (int ni = 0; ni < 2; ++ni)
                    acc[mi][ni] = __builtin_amdgcn_mfma_f32_16x16x32_bf16(
                        af[mi], bfr[ni], acc[mi][ni], 0, 0, 0);
        }
    }
#pragma unroll
    for (int mi = 0; mi < 4; ++mi)
#pragma unroll
        for (int ni = 0; ni < 2; ++ni) {
            int pxx = pc0 + (ni << 4) + lr;
            int pix = (hrow + 1) * 130 + pxx + 1;
            unsigned short pk[4];
#pragma unroll
            for (int r = 0; r < 4; ++r) pk[r] = f2bf(acc[mi][ni][r]);
            *(ushort4*)(ccT + (size_t)pix * 512 + 256 + (wv << 6) + (mi << 4) + (lg << 2))
                = *(ushort4*)pk;
        }
}

// ============ offset conv 512->18: channel-split partials, ccT staging ======
__global__ __launch_bounds__(256, 2) void off_part_k(
        const unsigned short* __restrict__ ccT,   // [130*130][512] bf16
        const unsigned short* __restrict__ pwTh,  // [9][32][512] bf16
        float* __restrict__ pbuf) {               // [4][32][HW] f32
    __shared__ __align__(16) unsigned short Bs[128][40];
    int b = blockIdx.x;
    int xcd = b & 7, slot = b >> 3;               // 64 slots
    int hrow = (xcd << 4) + (slot >> 2);
    int cg = slot & 3, c0 = cg << 7;
    int tid = threadIdx.x;
    int wv = tid >> 6, lane = tid & 63;
    int wr = wv >> 1, wc = wv & 1;                // o-half(16) x px-half(64)
    int lr = lane & 15, lg = lane >> 4;
    // staging map: 4 adjacent lanes cover the full 64B ch-window of one pixel
    int c4 = tid & 3, pxs = tid >> 2;             // pxs in 0..63, 2 px passes
    f32x4 acc[4];
#pragma unroll
    for (int j = 0; j < 4; ++j) acc[j] = (f32x4){0.f, 0.f, 0.f, 0.f};

    for (int kt = 0; kt < 9; ++kt) {
        int dy = kt / 3 - 1, dx = kt % 3 - 1;
        int pixb = (hrow + dy + 1) * 130 + dx + 1;
        for (int ksl = 0; ksl < 128; ksl += 32) {
            __syncthreads();
#pragma unroll
            for (int pp = 0; pp < 2; ++pp) {
                int px = pxs + (pp << 6);
                *(bf16x8*)&Bs[px][c4 << 3] =
                    *(const bf16x8*)(ccT + (size_t)(pixb + px) * 512 + c0 + ksl + (c4 << 3));
            }
            __syncthreads();
            bf16x8 af, bfr[4];
            af = *(const bf16x8*)(pwTh + (size_t)kt * 16384
                                  + (size_t)((wr << 4) + lr) * 512 + c0 + ksl + (lg << 3));
#pragma unroll
            for (int ni = 0; ni < 4; ++ni) {
                int n = (wc << 6) + (ni << 4) + lr;
                bfr[ni] = *(const bf16x8*)(&Bs[n][lg << 3]);
            }
#pragma unroll
            for (int ni = 0; ni < 4; ++ni)
                acc[ni] = __builtin_amdgcn_mfma_f32_16x16x32_bf16(af, bfr[ni], acc[ni], 0, 0, 0);
        }
    }
#pragma unroll
    for (int ni = 0; ni < 4; ++ni)
#pragma unroll
        for (int r = 0; r < 4; ++r) {
            int o = (wr << 4) + (lg << 2) + r;
            int p = (hrow << 7) + (wc << 6) + (ni << 4) + lr;
            pbuf[(size_t)((cg << 5) + o) * HW + p] = acc[ni][r];
        }
}

// ---- per-(pixel,k): sum 4 partials; IDX = pixel-index*512 into ccT ---------
__global__ __launch_bounds__(256) void make_idx_k(const float* __restrict__ pbuf,
                                                  const float* __restrict__ pb,
                                                  int4* __restrict__ IDX,
                                                  float4* __restrict__ WT) {
    int t = blockIdx.x * 256 + threadIdx.x;
    if (t >= 9 * HW) return;
    int k = t >> 14, p = t & 16383;
    int h = p >> 7, w = p & 127;
    float ox = 0.f, oy = 0.f;
#pragma unroll
    for (int cg = 0; cg < 4; ++cg) {
        ox += pbuf[(size_t)((cg << 5) + k) * HW + p];
        oy += pbuf[(size_t)((cg << 5) + 9 + k) * HW + p];
    }
    float px = ox + pb[k]     + (float)(k / 3 - 1) + (float)(h + 1);
    float py = oy + pb[9 + k] + (float)(k % 3 - 1) + (float)(w + 1);
    float fx = floorf(px), fy = floorf(py);
    float x0 = fminf(fmaxf(fx,        0.f), 129.f);
    float x1 = fminf(fmaxf(fx + 1.0f, 0.f), 129.f);
    float y0 = fminf(fmaxf(fy,        0.f), 129.f);
    float y1 = fminf(fmaxf(fy + 1.0f, 0.f), 129.f);
    float pxc = fminf(fmaxf(px, 0.f), 129.f);
    float pyc = fminf(fmaxf(py, 0.f), 129.f);
    float gx0 = 1.0f + x0 - pxc, gx1 = 1.0f - x1 + pxc;
    float gy0 = 1.0f + y0 - pyc, gy1 = 1.0f - y1 + pyc;
    int ix0 = (int)x0, ix1 = (int)x1, iy0 = (int)y0, iy1 = (int)y1;
    IDX[t] = make_int4((ix0 * 130 + iy0) << 9, (ix1 * 130 + iy1) << 9,
                       (ix0 * 130 + iy1) << 9, (ix1 * 130 + iy0) << 9);
    WT[t]  = make_float4(gx0 * gy0, gx1 * gy1, gx0 * gy1, gx1 * gy0);
}

// ============ deformable contraction v8: weights from global (frag-major), ==
// B-only LDS, publish(c+1) overlapped with MFMA(c).
// A-tile LDS staging removed entirely: weights are read per-wave as perfectly
// coalesced 1KB fragment loads from the frag-major layout (L2-resident,
// prefetched ~2 chunks ahead into named reg sets). LDS = Bs dbuf only (18KB);
// per-chunk LDS ops drop 136 -> 56. The gather-weighting VALU of chunk c+1 is
// issued BEFORE MFMA(c) in the same stream so the 2 waves/SIMD overlap VALU
// with MFMA instead of phase-locking behind the barrier (1 barrier/chunk).
__global__ __launch_bounds__(512, 2) void fam7_k(
        const unsigned short* __restrict__ ccT,    // [130*130][512] bf16
        const unsigned short* __restrict__ dcwF,   // frag-major weights
        const int4* __restrict__ IDX, const float4* __restrict__ WT,
        unsigned short* __restrict__ famh) {       // 256 bf16 planes PSH
    __shared__ __align__(16) unsigned short Bs[2][64][72];   // 18,432 B
    int b = blockIdx.x;                 // 256 blocks
    int xcd = b & 7, sl = b >> 3;       // 32 slots per XCD
    int nt = (xcd << 5) + sl;           // XCD owns 16 contiguous hrows
    int hrow = nt >> 1, pc0 = (nt & 1) << 6;
    int tid = threadIdx.x;
    int wv = tid >> 6, lane = tid & 63;
    int wo = wv >> 1, wp = wv & 1;      // o-quarter (64) x px-half (32)
    int lr = lane & 15, lg = lane >> 4;
    int pxg = tid >> 3, grp = tid & 7;  // staging: 64 px x 8 ch-groups of 8
    int p2 = (hrow << 7) + pc0 + pxg;   // this thread's gather pixel
    // per-wave frag base: chunk stride 16384, wo stride 4096, frag stride 512
    const unsigned short* wfb = dcwF + ((size_t)wo << 12) + ((size_t)lane << 3);
    f32x4 acc[4][2];
#pragma unroll
    for (int i = 0; i < 4; ++i)
#pragma unroll
        for (int j = 0; j < 2; ++j) acc[i][j] = (f32x4){0.f, 0.f, 0.f, 0.f};

#define AISSUEM(S, ch) do {                                                   \
    const unsigned short* ap_ = wfb + (size_t)(ch) * 16384;                   \
    S##f0 = *(const bf16x8*)(ap_);                                            \
    S##f1 = *(const bf16x8*)(ap_ + 512);                                      \
    S##f2 = *(const bf16x8*)(ap_ + 1024);                                     \
    S##f3 = *(const bf16x8*)(ap_ + 1536);                                     \
    S##f4 = *(const bf16x8*)(ap_ + 2048);                                     \
    S##f5 = *(const bf16x8*)(ap_ + 2560);                                     \
    S##f6 = *(const bf16x8*)(ap_ + 3072);                                     \
    S##f7 = *(const bf16x8*)(ap_ + 3584);                                     \
} while (0)

#define GISSUEM(S, ksn, idm, wtm) do {                                        \
    int cb_ = (ksn) + (grp << 3);                                             \
    S##v0 = *(const bf16x8*)(ccT + (idm).x + cb_);                            \
    S##v1 = *(const bf16x8*)(ccT + (idm).y + cb_);                            \
    S##v2 = *(const bf16x8*)(ccT + (idm).z + cb_);                            \
    S##v3 = *(const bf16x8*)(ccT + (idm).w + cb_);                            \
    S##wt = (wtm);                                                            \
} while (0)

#define PUBLISHM(S, bi) do {                                                  \
    unsigned short pk_[8];                                                    \
    _Pragma("unroll")                                                         \
    for (int e_ = 0; e_ < 8; ++e_) {                                          \
        float val_ = S##wt.x * bf2f((unsigned short)S##v0[e_])                \
                   + S##wt.y * bf2f((unsigned short)S##v1[e_])                \
                   + S##wt.z * bf2f((unsigned short)S##v2[e_])                \
                   + S##wt.w * bf2f((unsigned short)S##v3[e_]);               \
        pk_[e_] = f2bf(val_);                                                 \
    }                                                                         \
    *(bf16x8*)&Bs[bi][pxg][grp << 3] = *(bf16x8*)pk_;                         \
} while (0)

#define MFMAM(S, bi) do {                                                     \
    bf16x8 b00_ = *(const bf16x8*)(&Bs[bi][(wp << 5)      + lr][lg << 3]);    \
    bf16x8 b01_ = *(const bf16x8*)(&Bs[bi][(wp << 5) + 16 + lr][lg << 3]);    \
    acc[0][0] = __builtin_amdgcn_mfma_f32_16x16x32_bf16(S##f0, b00_, acc[0][0], 0, 0, 0); \
    acc[0][1] = __builtin_amdgcn_mfma_f32_16x16x32_bf16(S##f0, b01_, acc[0][1], 0, 0, 0); \
    acc[1][0] = __builtin_amdgcn_mfma_f32_16x16x32_bf16(S##f2, b00_, acc[1][0], 0, 0, 0); \
    acc[1][1] = __builtin_amdgcn_mfma_f32_16x16x32_bf16(S##f2, b01_, acc[1][1], 0, 0, 0); \
    acc[2][0] = __builtin_amdgcn_mfma_f32_16x16x32_bf16(S##f4, b00_, acc[2][0], 0, 0, 0); \
    acc[2][1] = __builtin_amdgcn_mfma_f32_16x16x32_bf16(S##f4, b01_, acc[2][1], 0, 0, 0); \
    acc[3][0] = __builtin_amdgcn_mfma_f32_16x16x32_bf16(S##f6, b00_, acc[3][0], 0, 0, 0); \
    acc[3][1] = __builtin_amdgcn_mfma_f32_16x16x32_bf16(S##f6, b01_, acc[3][1], 0, 0, 0); \
    bf16x8 b10_ = *(const bf16x8*)(&Bs[bi][(wp << 5)      + lr][32 + (lg << 3)]); \
    bf16x8 b11_ = *(const bf16x8*)(&Bs[bi][(wp << 5) + 16 + lr][32 + (lg << 3)]); \
    acc[0][0] = __builtin_amdgcn_mfma_f32_16x16x32_bf16(S##f1, b10_, acc[0][0], 0, 0, 0); \
    acc[0][1] = __builtin_amdgcn_mfma_f32_16x16x32_bf16(S##f1, b11_, acc[0][1], 0, 0, 0); \
    acc[1][0] = __builtin_amdgcn_mfma_f32_16x16x32_bf16(S##f3, b10_, acc[1][0], 0, 0, 0); \
    acc[1][1] = __builtin_amdgcn_mfma_f32_16x16x32_bf16(S##f3, b11_, acc[1][1], 0, 0, 0); \
    acc[2][0] = __builtin_amdgcn_mfma_f32_16x16x32_bf16(S##f5, b10_, acc[2][0], 0, 0, 0); \
    acc[2][1] = __builtin_amdgcn_mfma_f32_16x16x32_bf16(S##f5, b11_, acc[2][1], 0, 0, 0); \
    acc[3][0] = __builtin_amdgcn_mfma_f32_16x16x32_bf16(S##f7, b10_, acc[3][0], 0, 0, 0); \
    acc[3][1] = __builtin_amdgcn_mfma_f32_16x16x32_bf16(S##f7, b11_, acc[3][1], 0, 0, 0); \
} while (0)

    // named register sets (A = even-parity chunks, B = odd)
    bf16x8 Af0, Af1, Af2, Af3, Af4, Af5, Af6, Af7;
    bf16x8 Av0, Av1, Av2, Av3; float4 Awt;
    bf16x8 Bf0, Bf1, Bf2, Bf3, Bf4, Bf5, Bf6, Bf7;
    bf16x8 Bv0, Bv1, Bv2, Bv3; float4 Bwt;

    int4   idc = IDX[p2];           float4 wtc = WT[p2];
    int4   idn = IDX[16384 + p2];   float4 wtn = WT[16384 + p2];
    GISSUEM(A, 0, idc, wtc);        // gather chunk 0
    GISSUEM(B, 64, idc, wtc);       // gather chunk 1
    AISSUEM(A, 0);                  // frags chunk 0
    AISSUEM(B, 1);                  // frags chunk 1
    PUBLISHM(A, 0);                 // Bs[0] = chunk 0
    GISSUEM(A, 128, idc, wtc);      // gather chunk 2
    __syncthreads();

    for (int kt = 0; kt < 9; ++kt) {
        int ch0 = kt << 3;
        // j=0: mfma ch0 | publish ch0+1 | gather ch0+3 | frags ch0+2
        PUBLISHM(B, 1); GISSUEM(B, 192, idc, wtc);
        MFMAM(A, 0);    AISSUEM(A, ch0 + 2);
        __syncthreads();
        // j=1
        PUBLISHM(A, 0); GISSUEM(A, 256, idc, wtc);
        MFMAM(B, 1);    AISSUEM(B, ch0 + 3);
        __syncthreads();
        // j=2
        PUBLISHM(B, 1); GISSUEM(B, 320, idc, wtc);
        MFMAM(A, 0);    AISSUEM(A, ch0 + 4);
        __syncthreads();
        // j=3
        PUBLISHM(A, 0); GISSUEM(A, 384, idc, wtc);
        MFMAM(B, 1);    AISSUEM(B, ch0 + 5);
        __syncthreads();
        // j=4
        PUBLISHM(B, 1); GISSUEM(B, 448, idc, wtc);
        MFMAM(A, 0);    AISSUEM(A, ch0 + 6);
        __syncthreads();
        // j=5: gather crosses into kt+1 (ks 0, idn)
        PUBLISHM(A, 0); if (kt < 8) GISSUEM(A, 0, idn, wtn);
        MFMAM(B, 1);    AISSUEM(B, ch0 + 7);
        __syncthreads();
        // j=6: gather kt+1 ks64; frags cross into kt+1
        PUBLISHM(B, 1); if (kt < 8) GISSUEM(B, 64, idn, wtn);
        MFMAM(A, 0);    if (kt < 8) AISSUEM(A, ch0 + 8);
        __syncthreads();
        // j=7: publish kt+1's chunk 0; gather kt+1 ks128; frags kt+1 chunk 1
        if (kt < 8) { PUBLISHM(A, 0); GISSUEM(A, 128, idn, wtn); }
        MFMAM(B, 1);    if (kt < 8) AISSUEM(B, ch0 + 9);
        __syncthreads();
        idc = idn; wtc = wtn;
        if (kt < 7) {
            idn = IDX[((kt + 2) << 14) + p2];
            wtn = WT[((kt + 2) << 14) + p2];
        }
    }
#undef AISSUEM
#undef GISSUEM
#undef PUBLISHM
#undef MFMAM

    size_t rowb = (size_t)(hrow + 1) * SH;
#pragma unroll
    for (int mi = 0; mi < 4; ++mi)
#pragma unroll
        for (int ni = 0; ni < 2; ++ni)
#pragma unroll
            for (int r = 0; r < 4; ++r) {
                int o   = (wo << 6) + (mi << 4) + (lg << 2) + r;
                int pxx = pc0 + (wp << 5) + (ni << 4) + lr;
                float cf = bf2f(ccT[(size_t)((hrow + 1) * 130 + pxx + 1) * 512 + 256 + o]);
                famh[(size_t)o * PSH + rowb + pxx + 1] = f2bf(acc[mi][ni][r] + cf);
            }
}

// ============ 3x3 conv 256->256: full-M 256o x 32px tiles + BN + ReLU =======
__global__ __launch_bounds__(256, 2) void conv2_k(
        const unsigned short* __restrict__ inh,   // 256 bf16 planes PSH, ring=0
        const unsigned short* __restrict__ wTh,   // [9][256][256] bf16
        const float* __restrict__ gam, const float* __restrict__ bet,
        const float* __restrict__ mean, const float* __restrict__ var,
        float* __restrict__ out_flat,             // [256][HW] f32
        unsigned short* __restrict__ out_padh) {  // optional bf16 planes
    __shared__ __align__(16) unsigned short Bs[32][40];
    __shared__ float scs[256], bis[256];
    int b = blockIdx.x;
    int xcd = b & 7, slot = b >> 3;
    int nt = (xcd << 6) + slot;
    int hrow = nt >> 2, pc0 = (nt & 3) << 5;
    int tid = threadIdx.x;
    int wv = tid >> 6, lane = tid & 63;
    int lr = lane & 15, lg = lane >> 4;
    int pxl = tid & 31, cg = tid >> 5;
    {
        float sc = gam[tid] * rsqrtf(var[tid] + 1e-5f);
        scs[tid] = sc;
        bis[tid] = bet[tid] - mean[tid] * sc;
    }
    f32x4 acc[4][2];
#pragma unroll
    for (int i = 0; i < 4; ++i)
#pragma unroll
        for (int j = 0; j < 2; ++j) acc[i][j] = (f32x4){0.f, 0.f, 0.f, 0.f};

    for (int kt = 0; kt < 9; ++kt) {
        int dy = kt / 3 - 1, dx = kt % 3 - 1;
        const unsigned short* src = inh + (size_t)(hrow + dy + 1) * SH + (pc0 + pxl + dx + 1);
        const unsigned short* wk  = wTh + (size_t)kt * 65536;
        for (int ks = 0; ks < 256; ks += 32) {
            __syncthreads();
            unsigned short pk[4];
#pragma unroll
            for (int e = 0; e < 4; ++e) {
                int c = ks + (cg << 2) + e;
                pk[e] = src[(size_t)c * PSH];
            }
            *(short4*)&Bs[pxl][cg << 2] = *(short4*)pk;
            __syncthreads();
            bf16x8 af[4], bfr[2];
#pragma unroll
            for (int mi = 0; mi < 4; ++mi) {
                int o = (wv << 6) + (mi << 4) + lr;
                af[mi] = *(const bf16x8*)(wk + (size_t)o * 256 + ks + (lg << 3));
            }
#pragma unroll
            for (int ni = 0; ni < 2; ++ni) {
                int n = (ni << 4) + lr;
                bfr[ni] = *(const bf16x8*)(&Bs[n][lg << 3]);
            }
#pragma unroll
            for (int mi = 0; mi < 4; ++mi)
#pragma unroll
                for (int ni = 0; ni < 2; ++ni)
                    acc[mi][ni] = __builtin_amdgcn_mfma_f32_16x16x32_bf16(
                        af[mi], bfr[ni], acc[mi][ni], 0, 0, 0);
        }
    }
    size_t rowb = (size_t)(hrow + 1) * SH;
#pragma unroll
    for (int mi = 0; mi < 4; ++mi)
#pragma unroll
        for (int ni = 0; ni < 2; ++ni)
#pragma unroll
            for (int r = 0; r < 4; ++r) {
                int o   = (wv << 6) + (mi << 4) + (lg << 2) + r;
                int pxx = pc0 + (ni << 4) + lr;
                float rv = fmaxf(acc[mi][ni][r] * scs[o] + bis[o], 0.0f);
                out_flat[(size_t)o * HW + (hrow << 7) + pxx] = rv;
                if (out_padh)
                    out_padh[(size_t)o * PSH + rowb + pxx + 1] = f2bf(rv);
            }
}

extern "C" void kernel_launch(void* const* d_in, const int* in_sizes, int n_in,
                              void* d_out, int out_size, void* d_ws, size_t ws_size,
                              hipStream_t stream) {
    const float* x     = (const float*)d_in[0];
    const float* llf   = (const float*)d_in[1];
    const float* fm_w  = (const float*)d_in[2];
    const float* fs_w  = (const float*)d_in[3];
    const float* p_w   = (const float*)d_in[4];
    const float* p_b   = (const float*)d_in[5];
    const float* dc_w  = (const float*)d_in[6];
    const float* lc1_w = (const float*)d_in[7];
    const float* bn1g  = (const float*)d_in[8];
    const float* bn1b  = (const float*)d_in[9];
    const float* bn1m  = (const float*)d_in[10];
    const float* bn1v  = (const float*)d_in[11];
    const float* lc2_w = (const float*)d_in[12];
    const float* bn2g  = (const float*)d_in[13];
    const float* bn2b  = (const float*)d_in[14];
    const float* bn2m  = (const float*)d_in[15];
    const float* bn2v  = (const float*)d_in[16];
    float* out1 = (float*)d_out;
    float* out2 = out1 + (size_t)256 * HW;

    // d_out is WRITE-ONLY (pure outputs). All scratch lives in ws.
    if (ws_size < 79839232u) return;
    char* ws = (char*)d_ws;
    unsigned short* ccT   = (unsigned short*)ws;                // [0, 17,305,600)
    float*          ccpad = (float*)(ws + 17305600);            // V region
    float*          vbuf  = (float*)(ws + 17305600);
    unsigned short* famh  = (unsigned short*)(ws + 17305600);
    unsigned short* up1h  = (unsigned short*)(ws + 26091520);
    unsigned short* llfT  = (unsigned short*)(ws + 34877440);
    unsigned short* uT    = (unsigned short*)(ws + 43266048);
    unsigned short* fmwh  = (unsigned short*)(ws + 51654656);   // 131,072
    unsigned short* fswh  = (unsigned short*)(ws + 51785728);   // 131,072
    float*          ubuf  = (float*)(ws + 51916800);            // U region
    float*          pbuf  = (float*)(ws + 51916800);
    int4*           IDX   = (int4*)  (ws + 60305408);
    float4*         WT    = (float4*)(ws + 62664704);
    unsigned short* dcwTh  = (unsigned short*)(ws + 68694016);  // 2,359,296 (frag-major)
    unsigned short* lcw1Th = (unsigned short*)(ws + 71053312);  // 1,179,648
    unsigned short* lcw2Th = (unsigned short*)(ws + 72232960);  // 1,179,648
    unsigned short* pwTh   = (unsigned short*)(ws + 73412608);  //   294,912

    upsample_k<<<dim3(67, 256), 256, 0, stream>>>(x, ccpad);
    cvtT_k<<<dim3(16900), 256, 0, stream>>>(ccpad, ccT);          // ccpad dead after
    cvtT_flat_k<<<dim3(16384), 256, 0, stream>>>(llf, llfT, HW);
    w2bf_k<<<dim3(256), 256, 0, stream>>>(fm_w, fs_w, fmwh, fswh);
    vmfma_k<<<dim3(512), 256, 0, stream>>>(llfT, fmwh, vbuf);
    u_matmul_k<<<dim3(2, 256), 256, 0, stream>>>(llf, vbuf, ubuf);  // vbuf dead after
    cvtT_flat_k<<<dim3(16384), 256, 0, stream>>>(ubuf, uT, HW);   // ubuf dead after
    tr_dcwF_k<<<dim3(4608), 256, 0, stream>>>(dc_w, dcwTh);       // frag-major layout
    tr_ocK_k<<<dim3(2304), 256, 0, stream>>>(lc1_w, lcw1Th, 256);
    tr_ocK_k<<<dim3(2304), 256, 0, stream>>>(lc2_w, lcw2Th, 256);
    tr_pw_k<<<dim3(576), 256, 0, stream>>>(p_w, pwTh);
    cfmfma_k<<<dim3(512), 256, 0, stream>>>(uT, fswh, ccT);       // Cf -> ccT[:, 256:]
    ringT_k<<<dim3(520), 256, 0, stream>>>(ccT);                  // Cf ring = 0
    off_part_k<<<dim3(512), 256, 0, stream>>>(ccT, pwTh, pbuf);
    make_idx_k<<<dim3(576), 256, 0, stream>>>(pbuf, p_b, IDX, WT);
    zero_ring_h_k<<<dim3(521), 256, 0, stream>>>(famh, 256);
    zero_ring_h_k<<<dim3(521), 256, 0, stream>>>(up1h, 256);
    fam7_k<<<dim3(256), 512, 0, stream>>>(ccT, dcwTh, IDX, WT, famh);
    conv2_k<<<dim3(512), 256, 0, stream>>>(famh, lcw1Th, bn1g, bn1b, bn1m, bn1v,
                                           out1, up1h);
    conv2_k<<<dim3(512), 256, 0, stream>>>(up1h, lcw2Th, bn2g, bn2b, bn2m, bn2v,
                                           out2, nullptr);
}